// Round 1
// baseline (753.519 us; speedup 1.0000x reference)
//
#include <hip/hip_runtime.h>

#define F_IN 128

__device__ __forceinline__ float lrelu(float x) { return x >= 0.f ? x : 0.2f * x; }

// ---------------- CSR build ----------------
__global__ void k_deg(const int* __restrict__ ei, int e, int* __restrict__ deg) {
    int t = blockIdx.x * blockDim.x + threadIdx.x;
    if (t < e) atomicAdd(&deg[ei[e + t]], 1);   // ei[E..2E) = dst
}

__global__ void k_offsets(const int* __restrict__ deg, int* __restrict__ startp,
                          int* __restrict__ cursor, int n) {
    int t = blockIdx.x * blockDim.x + threadIdx.x;
    int lane = threadIdx.x & 63;
    int d = (t < n) ? deg[t] : 0;
    int pre = d;
    #pragma unroll
    for (int off = 1; off < 64; off <<= 1) {
        int u = __shfl_up(pre, off);
        if (lane >= off) pre += u;
    }
    int total = __shfl(pre, 63);
    int base = 0;
    if (lane == 0) base = atomicAdd(cursor, total);
    base = __shfl(base, 0);
    if (t < n) startp[t] = base + pre - d;      // exclusive within-wave prefix
}

__global__ void k_fill(const int* __restrict__ ei, int e, const int* __restrict__ startp,
                       int* __restrict__ fill, int* __restrict__ col) {
    int t = blockIdx.x * blockDim.x + threadIdx.x;
    if (t < e) {
        int s = ei[t];
        int dd = ei[e + t];
        int p = startp[dd] + atomicAdd(&fill[dd], 1);
        col[p] = s;
    }
}

// ---------------- fp32 tiled GEMM: C[M,Nc] = A[M,K] @ B[K,Nc] (+bias) ----------------
__global__ __launch_bounds__(256) void k_gemm(
    const float* __restrict__ A, const float* __restrict__ B,
    const float* __restrict__ bias, float* __restrict__ C,
    int M, int K, int Nc)
{
    __shared__ float As[16][64];
    __shared__ float Bs[16][64];
    const int tid = threadIdx.x;
    const int tx = tid & 15, ty = tid >> 4;
    const int bm = blockIdx.x * 64, bn = blockIdx.y * 64;
    const int arow = tid >> 2;         // 0..63
    const int akq  = (tid & 3) << 2;   // 0,4,8,12
    const int brow = tid >> 4;         // 0..15
    const int bcq  = (tid & 15) << 2;  // 0..60
    float acc[4][4] = {};
    for (int k0 = 0; k0 < K; k0 += 16) {
        float4 av = make_float4(0.f, 0.f, 0.f, 0.f);
        if (bm + arow < M)
            av = *reinterpret_cast<const float4*>(&A[(size_t)(bm + arow) * K + k0 + akq]);
        float4 bv = *reinterpret_cast<const float4*>(&B[(size_t)(k0 + brow) * Nc + bn + bcq]);
        __syncthreads();
        As[akq + 0][arow] = av.x;
        As[akq + 1][arow] = av.y;
        As[akq + 2][arow] = av.z;
        As[akq + 3][arow] = av.w;
        *reinterpret_cast<float4*>(&Bs[brow][bcq]) = bv;
        __syncthreads();
        #pragma unroll
        for (int k = 0; k < 16; k++) {
            float4 a = *reinterpret_cast<const float4*>(&As[k][ty << 2]);
            float4 b = *reinterpret_cast<const float4*>(&Bs[k][tx << 2]);
            float ar[4] = {a.x, a.y, a.z, a.w};
            float br[4] = {b.x, b.y, b.z, b.w};
            #pragma unroll
            for (int r = 0; r < 4; r++)
                #pragma unroll
                for (int c = 0; c < 4; c++)
                    acc[r][c] += ar[r] * br[c];
        }
    }
    #pragma unroll
    for (int r = 0; r < 4; r++) {
        int row = bm + (ty << 2) + r;
        if (row < M) {
            float4 v;
            float bx = 0.f, by = 0.f, bz = 0.f, bw = 0.f;
            if (bias) {
                bx = bias[bn + (tx << 2) + 0];
                by = bias[bn + (tx << 2) + 1];
                bz = bias[bn + (tx << 2) + 2];
                bw = bias[bn + (tx << 2) + 3];
            }
            v.x = acc[r][0] + bx; v.y = acc[r][1] + by;
            v.z = acc[r][2] + bz; v.w = acc[r][3] + bw;
            *reinterpret_cast<float4*>(&C[(size_t)row * Nc + bn + (tx << 2)]) = v;
        }
    }
}

// ---------------- attention coefficients: a_src/a_dst [N,H] ----------------
template<int H>
__global__ void k_attcoef(const float* __restrict__ h,
                          const float* __restrict__ watt_s,
                          const float* __restrict__ watt_d,
                          float* __restrict__ a_src, float* __restrict__ a_dst, int n)
{
    int wv = (blockIdx.x * blockDim.x + threadIdx.x) >> 6;
    int lane = threadIdx.x & 63;
    if (wv >= n) return;
    #pragma unroll
    for (int hh = 0; hh < H; hh++) {
        float v = h[(size_t)wv * (H * 64) + hh * 64 + lane];
        float s = v * watt_s[hh * 64 + lane];
        float d = v * watt_d[hh * 64 + lane];
        #pragma unroll
        for (int off = 32; off; off >>= 1) {
            s += __shfl_xor(s, off);
            d += __shfl_xor(d, off);
        }
        if (lane == 0) { a_src[wv * H + hh] = s; a_dst[wv * H + hh] = d; }
    }
}

// ---------------- softmax aggregation (one wave per dst node, self-loop implicit) ----------------
template<int H>
__global__ void k_agg(const float* __restrict__ h,
                      const float* __restrict__ asrc,
                      const float* __restrict__ adst,
                      const int* __restrict__ startp,
                      const int* __restrict__ deg,
                      const int* __restrict__ col,
                      const float* __restrict__ bias,
                      float* __restrict__ out, int n)
{
    int wv = (blockIdx.x * blockDim.x + threadIdx.x) >> 6;
    int lane = threadIdx.x & 63;
    if (wv >= n) return;
    const int i = wv;
    const int s0 = startp[i], d = deg[i];
    float ad[H], sv[H], mx[H];
    #pragma unroll
    for (int hh = 0; hh < H; hh++) {
        ad[hh] = adst[i * H + hh];
        sv[hh] = lrelu(asrc[i * H + hh] + ad[hh]);  // self edge score
        mx[hh] = sv[hh];
    }
    for (int t = lane; t < d; t += 64) {
        int s = col[s0 + t];
        #pragma unroll
        for (int hh = 0; hh < H; hh++)
            mx[hh] = fmaxf(mx[hh], lrelu(asrc[s * H + hh] + ad[hh]));
    }
    #pragma unroll
    for (int hh = 0; hh < H; hh++)
        #pragma unroll
        for (int off = 32; off; off >>= 1)
            mx[hh] = fmaxf(mx[hh], __shfl_xor(mx[hh], off));
    float sm[H];
    #pragma unroll
    for (int hh = 0; hh < H; hh++) sm[hh] = (lane == 0) ? __expf(sv[hh] - mx[hh]) : 0.f;
    for (int t = lane; t < d; t += 64) {
        int s = col[s0 + t];
        #pragma unroll
        for (int hh = 0; hh < H; hh++)
            sm[hh] += __expf(lrelu(asrc[s * H + hh] + ad[hh]) - mx[hh]);
    }
    #pragma unroll
    for (int hh = 0; hh < H; hh++) {
        #pragma unroll
        for (int off = 32; off; off >>= 1) sm[hh] += __shfl_xor(sm[hh], off);
        sm[hh] = 1.f / (sm[hh] + 1e-16f);
    }
    // weighted accumulate: lane = channel d, unrolled over heads
    float acc[H];
    #pragma unroll
    for (int hh = 0; hh < H; hh++)
        acc[hh] = __expf(sv[hh] - mx[hh]) * sm[hh] * h[(size_t)i * (H * 64) + hh * 64 + lane];
    for (int t = 0; t < d; t++) {
        int s = col[s0 + t];
        #pragma unroll
        for (int hh = 0; hh < H; hh++) {
            float w = __expf(lrelu(asrc[s * H + hh] + ad[hh]) - mx[hh]) * sm[hh];
            acc[hh] += w * h[(size_t)s * (H * 64) + hh * 64 + lane];
        }
    }
    #pragma unroll
    for (int hh = 0; hh < H; hh++)
        out[(size_t)i * (H * 64) + hh * 64 + lane] = acc[hh] + bias[hh * 64 + lane];
}

// ---------------- BatchNorm stats + normalize/relu ----------------
__global__ void k_bnstats(const float* __restrict__ x, int n, int c, float* __restrict__ accum)
{
    const int tid = threadIdx.x;
    const int colv = tid % c;
    const int rsub = tid / c;
    const int rpb = 256 / c;
    float s = 0.f, s2 = 0.f;
    for (int r = blockIdx.x * rpb + rsub; r < n; r += gridDim.x * rpb) {
        float v = x[(size_t)r * c + colv];
        s += v; s2 += v * v;
    }
    __shared__ float ls[256], ls2[256];
    ls[tid] = s; ls2[tid] = s2;
    __syncthreads();
    if (rsub == 0) {
        for (int k = 1; k < rpb; k++) { s += ls[k * c + colv]; s2 += ls2[k * c + colv]; }
        atomicAdd(&accum[colv], s);
        atomicAdd(&accum[c + colv], s2);
    }
}

__global__ void k_bnrelu(const float* __restrict__ x, float* __restrict__ y,
                         const float* __restrict__ accum, int n, int c)
{
    int idx = blockIdx.x * blockDim.x + threadIdx.x;
    int total = n * c;
    if (idx >= total) return;
    int colv = idx % c;
    float inv_n = 1.f / (float)n;
    float mu = accum[colv] * inv_n;
    float var = accum[c + colv] * inv_n - mu * mu;
    float v = (x[idx] - mu) * rsqrtf(var + 1e-5f);
    y[idx] = v > 0.f ? v : 0.f;
}

// ---------------- final head: [N,64] @ [64,2] + lb2 ----------------
__global__ void k_head(const float* __restrict__ h, const float* __restrict__ lw2,
                       const float* __restrict__ lb2, float* __restrict__ out, int n)
{
    int wv = (blockIdx.x * blockDim.x + threadIdx.x) >> 6;
    int lane = threadIdx.x & 63;
    if (wv >= n) return;
    float v = h[(size_t)wv * 64 + lane];
    float c0 = v * lw2[lane * 2 + 0];
    float c1 = v * lw2[lane * 2 + 1];
    #pragma unroll
    for (int off = 32; off; off >>= 1) {
        c0 += __shfl_xor(c0, off);
        c1 += __shfl_xor(c1, off);
    }
    if (lane == 0) {
        out[wv * 2 + 0] = c0 + lb2[0];
        out[wv * 2 + 1] = c1 + lb2[1];
    }
}

extern "C" void kernel_launch(void* const* d_in, const int* in_sizes, int n_in,
                              void* d_out, int out_size, void* d_ws, size_t ws_size,
                              hipStream_t stream)
{
    const float* x   = (const float*)d_in[0];
    const int*   ei  = (const int*)d_in[1];
    const float* W0  = (const float*)d_in[2];
    const float* as0 = (const float*)d_in[3];
    const float* ad0 = (const float*)d_in[4];
    const float* b0  = (const float*)d_in[5];
    const float* W1  = (const float*)d_in[6];
    const float* as1 = (const float*)d_in[7];
    const float* ad1 = (const float*)d_in[8];
    const float* b1  = (const float*)d_in[9];
    const float* W2  = (const float*)d_in[10];
    const float* as2 = (const float*)d_in[11];
    const float* ad2 = (const float*)d_in[12];
    const float* b2  = (const float*)d_in[13];
    const float* lw1 = (const float*)d_in[14];
    const float* lb1 = (const float*)d_in[15];
    const float* lw2 = (const float*)d_in[16];
    const float* lb2 = (const float*)d_in[17];
    float* out = (float*)d_out;

    const int n = in_sizes[0] / F_IN;   // 50000
    const int e = in_sizes[1] / 2;      // 800000

    // workspace partition (~108 MB)
    char* ws = (char*)d_ws;
    size_t off = 0;
    auto alloc = [&](size_t bytes) -> void* {
        void* p = ws + off;
        off += (bytes + 255) & ~(size_t)255;
        return p;
    };
    float* bufA  = (float*)alloc((size_t)n * 256 * 4);
    float* bufB  = (float*)alloc((size_t)n * 256 * 4);
    float* a_src = (float*)alloc((size_t)n * 4 * 4);
    float* a_dst = (float*)alloc((size_t)n * 4 * 4);
    float* stats = (float*)alloc(4 * 512 * 4);
    int* deg    = (int*)alloc((size_t)n * 4);
    int* fill   = (int*)alloc((size_t)n * 4);
    int* startp = (int*)alloc((size_t)n * 4);
    int* cursor = (int*)alloc(256);
    int* col    = (int*)alloc((size_t)e * 4);

    float* st0 = stats;
    float* st1 = stats + 512;
    float* st2 = stats + 1024;
    float* st3 = stats + 1536;

    hipMemsetAsync(stats, 0, 4 * 512 * 4, stream);
    hipMemsetAsync(deg, 0, (size_t)n * 4, stream);
    hipMemsetAsync(fill, 0, (size_t)n * 4, stream);
    hipMemsetAsync(cursor, 0, 4, stream);

    const int tpb = 256;
    // CSR build (graph shared by all 3 GAT layers)
    k_deg<<<(e + tpb - 1) / tpb, tpb, 0, stream>>>(ei, e, deg);
    k_offsets<<<(n + tpb - 1) / tpb, tpb, 0, stream>>>(deg, startp, cursor, n);
    k_fill<<<(e + tpb - 1) / tpb, tpb, 0, stream>>>(ei, e, startp, fill, col);

    const int wgrid = (n + 3) / 4;                 // 4 waves (nodes) per 256-thread block
    const int rowTiles = (n + 63) / 64;

    // Layer 0: GAT 128 -> 4x64
    k_gemm<<<dim3(rowTiles, 4), 256, 0, stream>>>(x, W0, nullptr, bufA, n, 128, 256);
    k_attcoef<4><<<wgrid, 256, 0, stream>>>(bufA, as0, ad0, a_src, a_dst, n);
    k_agg<4><<<wgrid, 256, 0, stream>>>(bufA, a_src, a_dst, startp, deg, col, b0, bufB, n);
    k_bnstats<<<256, 256, 0, stream>>>(bufB, n, 256, st0);
    k_bnrelu<<<((size_t)n * 256 + 255) / 256, 256, 0, stream>>>(bufB, bufA, st0, n, 256);

    // Layer 1: GAT 256 -> 64
    k_gemm<<<dim3(rowTiles, 1), 256, 0, stream>>>(bufA, W1, nullptr, bufB, n, 256, 64);
    k_attcoef<1><<<wgrid, 256, 0, stream>>>(bufB, as1, ad1, a_src, a_dst, n);
    k_agg<1><<<wgrid, 256, 0, stream>>>(bufB, a_src, a_dst, startp, deg, col, b1, bufA, n);
    k_bnstats<<<256, 256, 0, stream>>>(bufA, n, 64, st1);
    k_bnrelu<<<((size_t)n * 64 + 255) / 256, 256, 0, stream>>>(bufA, bufB, st1, n, 64);

    // Layer 2: GAT 64 -> 64
    k_gemm<<<dim3(rowTiles, 1), 256, 0, stream>>>(bufB, W2, nullptr, bufA, n, 64, 64);
    k_attcoef<1><<<wgrid, 256, 0, stream>>>(bufA, as2, ad2, a_src, a_dst, n);
    k_agg<1><<<wgrid, 256, 0, stream>>>(bufA, a_src, a_dst, startp, deg, col, b2, bufB, n);
    k_bnstats<<<256, 256, 0, stream>>>(bufB, n, 64, st2);
    k_bnrelu<<<((size_t)n * 64 + 255) / 256, 256, 0, stream>>>(bufB, bufA, st2, n, 64);

    // MLP head: linear 64->64 + BN + ReLU, then 64->2
    k_gemm<<<dim3(rowTiles, 1), 256, 0, stream>>>(bufA, lw1, lb1, bufB, n, 64, 64);
    k_bnstats<<<256, 256, 0, stream>>>(bufB, n, 64, st3);
    k_bnrelu<<<((size_t)n * 64 + 255) / 256, 256, 0, stream>>>(bufB, bufA, st3, n, 64);

    k_head<<<wgrid, 256, 0, stream>>>(bufA, lw2, lb2, out, n);
}

// Round 2
// 529.181 us; speedup vs baseline: 1.4239x; 1.4239x over previous
//
#include <hip/hip_runtime.h>

#define F_IN 128
#define EPS_BN 1e-5f

__device__ __forceinline__ float lrelu(float x) { return x >= 0.f ? x : 0.2f * x; }
__device__ __forceinline__ unsigned short f2bf(float f) {
    unsigned int u = __float_as_uint(f);
    u += 0x7FFFu + ((u >> 16) & 1u);
    return (unsigned short)(u >> 16);
}
__device__ __forceinline__ float bf2f(unsigned short s) {
    return __uint_as_float(((unsigned int)s) << 16);
}

// ---------------- CSR build ----------------
__global__ void k_deg(const int* __restrict__ ei, int e, int* __restrict__ deg) {
    int t = blockIdx.x * blockDim.x + threadIdx.x;
    if (t < e) atomicAdd(&deg[ei[e + t]], 1);   // ei[E..2E) = dst
}

__global__ void k_offsets(const int* __restrict__ deg, int* __restrict__ startp,
                          int* __restrict__ cursor, int n) {
    int t = blockIdx.x * blockDim.x + threadIdx.x;
    int lane = threadIdx.x & 63;
    int d = (t < n) ? deg[t] : 0;
    int pre = d;
    #pragma unroll
    for (int off = 1; off < 64; off <<= 1) {
        int u = __shfl_up(pre, off);
        if (lane >= off) pre += u;
    }
    int total = __shfl(pre, 63);
    int base = 0;
    if (lane == 0) base = atomicAdd(cursor, total);
    base = __shfl(base, 0);
    if (t < n) startp[t] = base + pre - d;
}

__global__ void k_fill(const int* __restrict__ ei, int e, const int* __restrict__ startp,
                       int* __restrict__ fill, int* __restrict__ col) {
    int t = blockIdx.x * blockDim.x + threadIdx.x;
    if (t < e) {
        int s = ei[t];
        int dd = ei[e + t];
        int p = startp[dd] + atomicAdd(&fill[dd], 1);
        col[p] = s;
    }
}

// ---------------- fused GEMM ----------------
// C[M,Nc] = f(A)[M,K] @ Bw[K,Nc]; f = identity or BN-normalize+ReLU (mu/rstd).
// ATT: write C as bf16 (gather buffer) and compute per-row, per-head attention
//      dots a_src/a_dst in the epilogue (head = 64-col tile = blockIdx.y).
// !ATT: write C as fp32 + bias.
template<bool BN, bool ATT>
__global__ __launch_bounds__(256) void k_gemm(
    const float* __restrict__ A, const float* __restrict__ Bw,
    const float* __restrict__ bias,
    const float* __restrict__ mu, const float* __restrict__ rstd,
    const float* __restrict__ att_s, const float* __restrict__ att_d,
    float* __restrict__ a_src, float* __restrict__ a_dst, int H,
    float* __restrict__ Cf, unsigned short* __restrict__ Cb,
    int M, int K, int Nc)
{
    __shared__ float As[16][64];
    __shared__ float Bs[16][64];
    __shared__ float red_s[64][17];
    __shared__ float red_d[64][17];
    const int tid = threadIdx.x;
    const int tx = tid & 15, ty = tid >> 4;
    const int bm = blockIdx.x * 64, bn = blockIdx.y * 64;
    const int arow = tid >> 2;
    const int akq  = (tid & 3) << 2;
    const int brow = tid >> 4;
    const int bcq  = (tid & 15) << 2;
    float acc[4][4] = {};
    for (int k0 = 0; k0 < K; k0 += 16) {
        float4 av = make_float4(0.f, 0.f, 0.f, 0.f);
        if (bm + arow < M) {
            av = *reinterpret_cast<const float4*>(&A[(size_t)(bm + arow) * K + k0 + akq]);
            if constexpr (BN) {
                float4 m  = *reinterpret_cast<const float4*>(&mu[k0 + akq]);
                float4 rs = *reinterpret_cast<const float4*>(&rstd[k0 + akq]);
                av.x = fmaxf((av.x - m.x) * rs.x, 0.f);
                av.y = fmaxf((av.y - m.y) * rs.y, 0.f);
                av.z = fmaxf((av.z - m.z) * rs.z, 0.f);
                av.w = fmaxf((av.w - m.w) * rs.w, 0.f);
            }
        }
        float4 bv = *reinterpret_cast<const float4*>(&Bw[(size_t)(k0 + brow) * Nc + bn + bcq]);
        __syncthreads();
        As[akq + 0][arow] = av.x;
        As[akq + 1][arow] = av.y;
        As[akq + 2][arow] = av.z;
        As[akq + 3][arow] = av.w;
        *reinterpret_cast<float4*>(&Bs[brow][bcq]) = bv;
        __syncthreads();
        #pragma unroll
        for (int k = 0; k < 16; k++) {
            float4 a = *reinterpret_cast<const float4*>(&As[k][ty << 2]);
            float4 b = *reinterpret_cast<const float4*>(&Bs[k][tx << 2]);
            float ar[4] = {a.x, a.y, a.z, a.w};
            float br[4] = {b.x, b.y, b.z, b.w};
            #pragma unroll
            for (int r = 0; r < 4; r++)
                #pragma unroll
                for (int c = 0; c < 4; c++)
                    acc[r][c] += ar[r] * br[c];
        }
    }
    if constexpr (ATT) {
        float4 wsv = *reinterpret_cast<const float4*>(&att_s[bn + (tx << 2)]);
        float4 wdv = *reinterpret_cast<const float4*>(&att_d[bn + (tx << 2)]);
        #pragma unroll
        for (int r = 0; r < 4; r++) {
            int rit = (ty << 2) + r;
            red_s[rit][tx] = acc[r][0]*wsv.x + acc[r][1]*wsv.y + acc[r][2]*wsv.z + acc[r][3]*wsv.w;
            red_d[rit][tx] = acc[r][0]*wdv.x + acc[r][1]*wdv.y + acc[r][2]*wdv.z + acc[r][3]*wdv.w;
            int row = bm + rit;
            if (row < M) {
                ushort4 o;
                o.x = f2bf(acc[r][0]); o.y = f2bf(acc[r][1]);
                o.z = f2bf(acc[r][2]); o.w = f2bf(acc[r][3]);
                *reinterpret_cast<ushort4*>(&Cb[(size_t)row * Nc + bn + (tx << 2)]) = o;
            }
        }
        __syncthreads();
        if (tid < 64) {
            float s = 0.f, dd = 0.f;
            #pragma unroll
            for (int k = 0; k < 16; k++) { s += red_s[tid][k]; dd += red_d[tid][k]; }
            int row = bm + tid;
            if (row < M) {
                int hh = bn >> 6;
                a_src[(size_t)row * H + hh] = s;
                a_dst[(size_t)row * H + hh] = dd;
            }
        }
    } else {
        #pragma unroll
        for (int r = 0; r < 4; r++) {
            int row = bm + (ty << 2) + r;
            if (row < M) {
                float4 v;
                float4 bb = *reinterpret_cast<const float4*>(&bias[bn + (tx << 2)]);
                v.x = acc[r][0] + bb.x; v.y = acc[r][1] + bb.y;
                v.z = acc[r][2] + bb.z; v.w = acc[r][3] + bb.w;
                *reinterpret_cast<float4*>(&Cf[(size_t)row * Nc + bn + (tx << 2)]) = v;
            }
        }
    }
}

// ---------------- single-pass online softmax aggregation, H=4 ----------------
// One wave per dst node; lane owns 4 consecutive channels (head = lane>>4).
__global__ void k_agg4(const unsigned short* __restrict__ hb,
                       const float* __restrict__ asrc, const float* __restrict__ adst,
                       const int* __restrict__ startp, const int* __restrict__ deg,
                       const int* __restrict__ col, const float* __restrict__ bias,
                       float* __restrict__ out, int n)
{
    int wv = (blockIdx.x * blockDim.x + threadIdx.x) >> 6;
    int lane = threadIdx.x & 63;
    if (wv >= n) return;
    const int s0 = startp[wv], d = deg[wv];
    const int hs = lane >> 4;
    const float adh = adst[wv * 4 + hs];
    const float eself = lrelu(asrc[wv * 4 + hs] + adh);
    float mx = eself, sm = 1.f;
    size_t cb = (size_t)wv * 256 + (lane << 2);
    ushort4 v = *reinterpret_cast<const ushort4*>(&hb[cb]);
    float a0 = bf2f(v.x), a1 = bf2f(v.y), a2 = bf2f(v.z), a3 = bf2f(v.w);
    for (int t = 0; t < d; t++) {
        int s = col[s0 + t];
        float e = lrelu(asrc[s * 4 + hs] + adh);
        ushort4 u = *reinterpret_cast<const ushort4*>(&hb[(size_t)s * 256 + (lane << 2)]);
        float h0 = bf2f(u.x), h1 = bf2f(u.y), h2 = bf2f(u.z), h3 = bf2f(u.w);
        if (e > mx) {
            float r = __expf(mx - e);
            sm = sm * r + 1.f;
            a0 = a0 * r + h0; a1 = a1 * r + h1; a2 = a2 * r + h2; a3 = a3 * r + h3;
            mx = e;
        } else {
            float w = __expf(e - mx);
            sm += w;
            a0 += w * h0; a1 += w * h1; a2 += w * h2; a3 += w * h3;
        }
    }
    float rinv = 1.f / (sm + 1e-16f);
    const float4 bv = *reinterpret_cast<const float4*>(&bias[lane << 2]);
    float4 o;
    o.x = a0 * rinv + bv.x; o.y = a1 * rinv + bv.y;
    o.z = a2 * rinv + bv.z; o.w = a3 * rinv + bv.w;
    *reinterpret_cast<float4*>(&out[cb]) = o;
}

// ---------------- single-pass online softmax aggregation, H=1 ----------------
// One wave per dst node; 4 edges/iter (one per 16-lane group), cross-group merge.
__global__ void k_agg1(const unsigned short* __restrict__ hb,
                       const float* __restrict__ asrc, const float* __restrict__ adst,
                       const int* __restrict__ startp, const int* __restrict__ deg,
                       const int* __restrict__ col, const float* __restrict__ bias,
                       float* __restrict__ out, int n)
{
    int wv = (blockIdx.x * blockDim.x + threadIdx.x) >> 6;
    int lane = threadIdx.x & 63;
    if (wv >= n) return;
    const int s0 = startp[wv], d = deg[wv];
    const int g = lane >> 4, l16 = lane & 15;
    const float adv = adst[wv];
    size_t cb = (size_t)wv * 64 + (l16 << 2);
    float mx, sm, a0, a1, a2, a3;
    if (g == 0) {
        float e = lrelu(asrc[wv] + adv);
        ushort4 v = *reinterpret_cast<const ushort4*>(&hb[cb]);
        mx = e; sm = 1.f;
        a0 = bf2f(v.x); a1 = bf2f(v.y); a2 = bf2f(v.z); a3 = bf2f(v.w);
    } else {
        mx = -1e30f; sm = 0.f; a0 = a1 = a2 = a3 = 0.f;
    }
    for (int t0 = 0; t0 < d; t0 += 4) {
        int t = t0 + g;
        if (t < d) {
            int s = col[s0 + t];
            float e = lrelu(asrc[s] + adv);
            ushort4 u = *reinterpret_cast<const ushort4*>(&hb[(size_t)s * 64 + (l16 << 2)]);
            float h0 = bf2f(u.x), h1 = bf2f(u.y), h2 = bf2f(u.z), h3 = bf2f(u.w);
            if (e > mx) {
                float r = __expf(mx - e);
                sm = sm * r + 1.f;
                a0 = a0 * r + h0; a1 = a1 * r + h1; a2 = a2 * r + h2; a3 = a3 * r + h3;
                mx = e;
            } else {
                float w = __expf(e - mx);
                sm += w;
                a0 += w * h0; a1 += w * h1; a2 += w * h2; a3 += w * h3;
            }
        }
    }
    #pragma unroll
    for (int off = 16; off <= 32; off <<= 1) {
        float om  = __shfl_xor(mx, off);
        float osm = __shfl_xor(sm, off);
        float b0 = __shfl_xor(a0, off), b1 = __shfl_xor(a1, off);
        float b2 = __shfl_xor(a2, off), b3 = __shfl_xor(a3, off);
        float nm = fmaxf(mx, om);
        float ea = __expf(mx - nm), eb = __expf(om - nm);
        sm = sm * ea + osm * eb;
        a0 = a0 * ea + b0 * eb; a1 = a1 * ea + b1 * eb;
        a2 = a2 * ea + b2 * eb; a3 = a3 * ea + b3 * eb;
        mx = nm;
    }
    if (g == 0) {
        float rinv = 1.f / (sm + 1e-16f);
        float4 bv = *reinterpret_cast<const float4*>(&bias[l16 << 2]);
        float4 o;
        o.x = a0 * rinv + bv.x; o.y = a1 * rinv + bv.y;
        o.z = a2 * rinv + bv.z; o.w = a3 * rinv + bv.w;
        *reinterpret_cast<float4*>(&out[cb]) = o;
    }
}

// ---------------- BatchNorm stats (sum, sumsq) + finalize (mu, rstd) ----------------
__global__ void k_bnstats(const float* __restrict__ x, int n, int c, float* __restrict__ accum)
{
    const int tid = threadIdx.x;
    const int colv = tid % c;
    const int rsub = tid / c;
    const int rpb = 256 / c;
    float s = 0.f, s2 = 0.f;
    for (int r = blockIdx.x * rpb + rsub; r < n; r += gridDim.x * rpb) {
        float v = x[(size_t)r * c + colv];
        s += v; s2 += v * v;
    }
    __shared__ float ls[256], ls2[256];
    ls[tid] = s; ls2[tid] = s2;
    __syncthreads();
    if (rsub == 0) {
        for (int k = 1; k < rpb; k++) { s += ls[k * c + colv]; s2 += ls2[k * c + colv]; }
        atomicAdd(&accum[colv], s);
        atomicAdd(&accum[c + colv], s2);
    }
}

__global__ void k_bnfinal(float* __restrict__ st, int c, float invN)
{
    int t = threadIdx.x;
    if (t < c) {
        float m = st[t] * invN;
        float var = st[c + t] * invN - m * m;
        st[2 * c + t] = m;
        st[3 * c + t] = rsqrtf(var + EPS_BN);
    }
}

// ---------------- final head: relu(bn(h)) @ lw2 + lb2 ----------------
__global__ void k_head(const float* __restrict__ h, const float* __restrict__ st,
                       const float* __restrict__ lw2, const float* __restrict__ lb2,
                       float* __restrict__ out, int n)
{
    int wv = (blockIdx.x * blockDim.x + threadIdx.x) >> 6;
    int lane = threadIdx.x & 63;
    if (wv >= n) return;
    float m  = st[128 + lane];
    float rs = st[192 + lane];
    float v = fmaxf((h[(size_t)wv * 64 + lane] - m) * rs, 0.f);
    float c0 = v * lw2[lane * 2 + 0];
    float c1 = v * lw2[lane * 2 + 1];
    #pragma unroll
    for (int off = 32; off; off >>= 1) {
        c0 += __shfl_xor(c0, off);
        c1 += __shfl_xor(c1, off);
    }
    if (lane == 0) {
        out[wv * 2 + 0] = c0 + lb2[0];
        out[wv * 2 + 1] = c1 + lb2[1];
    }
}

extern "C" void kernel_launch(void* const* d_in, const int* in_sizes, int n_in,
                              void* d_out, int out_size, void* d_ws, size_t ws_size,
                              hipStream_t stream)
{
    const float* x   = (const float*)d_in[0];
    const int*   ei  = (const int*)d_in[1];
    const float* W0  = (const float*)d_in[2];
    const float* as0 = (const float*)d_in[3];
    const float* ad0 = (const float*)d_in[4];
    const float* b0  = (const float*)d_in[5];
    const float* W1  = (const float*)d_in[6];
    const float* as1 = (const float*)d_in[7];
    const float* ad1 = (const float*)d_in[8];
    const float* b1  = (const float*)d_in[9];
    const float* W2  = (const float*)d_in[10];
    const float* as2 = (const float*)d_in[11];
    const float* ad2 = (const float*)d_in[12];
    const float* b2  = (const float*)d_in[13];
    const float* lw1 = (const float*)d_in[14];
    const float* lb1 = (const float*)d_in[15];
    const float* lw2 = (const float*)d_in[16];
    const float* lb2 = (const float*)d_in[17];
    float* out = (float*)d_out;

    const int n = in_sizes[0] / F_IN;   // 50000
    const int e = in_sizes[1] / 2;      // 800000

    char* ws = (char*)d_ws;
    size_t off = 0;
    auto alloc = [&](size_t bytes) -> void* {
        void* p = ws + off;
        off += (bytes + 255) & ~(size_t)255;
        return p;
    };
    float* B            = (float*)alloc((size_t)n * 256 * 4);           // agg outputs (51.2 MB)
    unsigned short* Hb  = (unsigned short*)alloc((size_t)n * 256 * 2);  // bf16 gather buf (25.6 MB)
    float* g3           = (float*)Hb;                                   // alias: MLP out after Hb dead
    float* a_src = (float*)alloc((size_t)n * 4 * 4);
    float* a_dst = (float*)alloc((size_t)n * 4 * 4);
    float* stats = (float*)alloc(4 * 1024 * 4);
    int* deg    = (int*)alloc((size_t)n * 4);
    int* fill   = (int*)alloc((size_t)n * 4);
    int* startp = (int*)alloc((size_t)n * 4);
    int* cursor = (int*)alloc(256);
    int* col    = (int*)alloc((size_t)e * 4);

    float* st0 = stats;
    float* st1 = stats + 1024;
    float* st2 = stats + 2048;
    float* st3 = stats + 3072;
    const float invN = 1.f / (float)n;

    hipMemsetAsync(stats, 0, 4 * 1024 * 4, stream);
    hipMemsetAsync(deg, 0, (size_t)n * 4, stream);
    hipMemsetAsync(fill, 0, (size_t)n * 4, stream);
    hipMemsetAsync(cursor, 0, 4, stream);

    const int tpb = 256;
    k_deg<<<(e + tpb - 1) / tpb, tpb, 0, stream>>>(ei, e, deg);
    k_offsets<<<(n + tpb - 1) / tpb, tpb, 0, stream>>>(deg, startp, cursor, n);
    k_fill<<<(e + tpb - 1) / tpb, tpb, 0, stream>>>(ei, e, startp, fill, col);

    const int wgrid = (n + 3) / 4;
    const int rowTiles = (n + 63) / 64;

    // Layer 0: GAT 128 -> 4x64 (no BN on input x)
    k_gemm<false, true><<<dim3(rowTiles, 4), 256, 0, stream>>>(
        x, W0, nullptr, nullptr, nullptr, as0, ad0, a_src, a_dst, 4,
        nullptr, Hb, n, 128, 256);
    k_agg4<<<wgrid, 256, 0, stream>>>(Hb, a_src, a_dst, startp, deg, col, b0, B, n);
    k_bnstats<<<256, 256, 0, stream>>>(B, n, 256, st0);
    k_bnfinal<<<1, 256, 0, stream>>>(st0, 256, invN);

    // Layer 1: GAT 256 -> 64 (BN+ReLU fused into A-load)
    k_gemm<true, true><<<dim3(rowTiles, 1), 256, 0, stream>>>(
        B, W1, nullptr, st0 + 512, st0 + 768, as1, ad1, a_src, a_dst, 1,
        nullptr, Hb, n, 256, 64);
    k_agg1<<<wgrid, 256, 0, stream>>>(Hb, a_src, a_dst, startp, deg, col, b1, B, n);
    k_bnstats<<<256, 256, 0, stream>>>(B, n, 64, st1);
    k_bnfinal<<<1, 256, 0, stream>>>(st1, 64, invN);

    // Layer 2: GAT 64 -> 64
    k_gemm<true, true><<<dim3(rowTiles, 1), 256, 0, stream>>>(
        B, W2, nullptr, st1 + 128, st1 + 192, as2, ad2, a_src, a_dst, 1,
        nullptr, Hb, n, 64, 64);
    k_agg1<<<wgrid, 256, 0, stream>>>(Hb, a_src, a_dst, startp, deg, col, b2, B, n);
    k_bnstats<<<256, 256, 0, stream>>>(B, n, 64, st2);
    k_bnfinal<<<1, 256, 0, stream>>>(st2, 64, invN);

    // MLP: relu(bn(o2)) @ lw1 + lb1  (g3 aliases Hb, which is dead now)
    k_gemm<true, false><<<dim3(rowTiles, 1), 256, 0, stream>>>(
        B, lw1, lb1, st2 + 128, st2 + 192, nullptr, nullptr, nullptr, nullptr, 1,
        g3, nullptr, n, 64, 64);
    k_bnstats<<<256, 256, 0, stream>>>(g3, n, 64, st3);
    k_bnfinal<<<1, 256, 0, stream>>>(st3, 64, invN);

    // head: relu(bn(g3)) @ lw2 + lb2
    k_head<<<wgrid, 256, 0, stream>>>(g3, st3, lw2, lb2, out, n);
}

// Round 3
// 527.989 us; speedup vs baseline: 1.4271x; 1.0023x over previous
//
#include <hip/hip_runtime.h>

#define F_IN 128
#define EPS_BN 1e-5f

__device__ __forceinline__ float lrelu(float x) { return x >= 0.f ? x : 0.2f * x; }
__device__ __forceinline__ unsigned short f2bf(float f) {
    unsigned int u = __float_as_uint(f);
    u += 0x7FFFu + ((u >> 16) & 1u);
    return (unsigned short)(u >> 16);
}
__device__ __forceinline__ float bf2f(unsigned short s) {
    return __uint_as_float(((unsigned int)s) << 16);
}

// ---------------- CSR build ----------------
__global__ void k_deg(const int* __restrict__ ei, int e, int* __restrict__ deg) {
    int t = blockIdx.x * blockDim.x + threadIdx.x;
    if (t < e) atomicAdd(&deg[ei[e + t]], 1);   // ei[E..2E) = dst
}

__global__ void k_offsets(const int* __restrict__ deg, int* __restrict__ startp,
                          int* __restrict__ cursor, int n) {
    int t = blockIdx.x * blockDim.x + threadIdx.x;
    int lane = threadIdx.x & 63;
    int d = (t < n) ? deg[t] : 0;
    int pre = d;
    #pragma unroll
    for (int off = 1; off < 64; off <<= 1) {
        int u = __shfl_up(pre, off);
        if (lane >= off) pre += u;
    }
    int total = __shfl(pre, 63);
    int base = 0;
    if (lane == 0) base = atomicAdd(cursor, total);
    base = __shfl(base, 0);
    if (t < n) startp[t] = base + pre - d;
}

__global__ void k_fill(const int* __restrict__ ei, int e, const int* __restrict__ startp,
                       int* __restrict__ fill, int* __restrict__ col) {
    int t = blockIdx.x * blockDim.x + threadIdx.x;
    if (t < e) {
        int s = ei[t];
        int dd = ei[e + t];
        int p = startp[dd] + atomicAdd(&fill[dd], 1);
        col[p] = s;
    }
}

// ---------------- fused GEMM ----------------
template<bool BN, bool ATT>
__global__ __launch_bounds__(256) void k_gemm(
    const float* __restrict__ A, const float* __restrict__ Bw,
    const float* __restrict__ bias,
    const float* __restrict__ mu, const float* __restrict__ rstd,
    const float* __restrict__ att_s, const float* __restrict__ att_d,
    float* __restrict__ a_src, float* __restrict__ a_dst, int H,
    float* __restrict__ Cf, unsigned short* __restrict__ Cb,
    int M, int K, int Nc)
{
    __shared__ float As[16][64];
    __shared__ float Bs[16][64];
    __shared__ float red_s[64][17];
    __shared__ float red_d[64][17];
    const int tid = threadIdx.x;
    const int tx = tid & 15, ty = tid >> 4;
    const int bm = blockIdx.x * 64, bn = blockIdx.y * 64;
    const int arow = tid >> 2;
    const int akq  = (tid & 3) << 2;
    const int brow = tid >> 4;
    const int bcq  = (tid & 15) << 2;
    float acc[4][4] = {};
    for (int k0 = 0; k0 < K; k0 += 16) {
        float4 av = make_float4(0.f, 0.f, 0.f, 0.f);
        if (bm + arow < M) {
            av = *reinterpret_cast<const float4*>(&A[(size_t)(bm + arow) * K + k0 + akq]);
            if constexpr (BN) {
                float4 m  = *reinterpret_cast<const float4*>(&mu[k0 + akq]);
                float4 rs = *reinterpret_cast<const float4*>(&rstd[k0 + akq]);
                av.x = fmaxf((av.x - m.x) * rs.x, 0.f);
                av.y = fmaxf((av.y - m.y) * rs.y, 0.f);
                av.z = fmaxf((av.z - m.z) * rs.z, 0.f);
                av.w = fmaxf((av.w - m.w) * rs.w, 0.f);
            }
        }
        float4 bv = *reinterpret_cast<const float4*>(&Bw[(size_t)(k0 + brow) * Nc + bn + bcq]);
        __syncthreads();
        As[akq + 0][arow] = av.x;
        As[akq + 1][arow] = av.y;
        As[akq + 2][arow] = av.z;
        As[akq + 3][arow] = av.w;
        *reinterpret_cast<float4*>(&Bs[brow][bcq]) = bv;
        __syncthreads();
        #pragma unroll
        for (int k = 0; k < 16; k++) {
            float4 a = *reinterpret_cast<const float4*>(&As[k][ty << 2]);
            float4 b = *reinterpret_cast<const float4*>(&Bs[k][tx << 2]);
            float ar[4] = {a.x, a.y, a.z, a.w};
            float br[4] = {b.x, b.y, b.z, b.w};
            #pragma unroll
            for (int r = 0; r < 4; r++)
                #pragma unroll
                for (int c = 0; c < 4; c++)
                    acc[r][c] += ar[r] * br[c];
        }
    }
    if constexpr (ATT) {
        float4 wsv = *reinterpret_cast<const float4*>(&att_s[bn + (tx << 2)]);
        float4 wdv = *reinterpret_cast<const float4*>(&att_d[bn + (tx << 2)]);
        #pragma unroll
        for (int r = 0; r < 4; r++) {
            int rit = (ty << 2) + r;
            red_s[rit][tx] = acc[r][0]*wsv.x + acc[r][1]*wsv.y + acc[r][2]*wsv.z + acc[r][3]*wsv.w;
            red_d[rit][tx] = acc[r][0]*wdv.x + acc[r][1]*wdv.y + acc[r][2]*wdv.z + acc[r][3]*wdv.w;
            int row = bm + rit;
            if (row < M) {
                ushort4 o;
                o.x = f2bf(acc[r][0]); o.y = f2bf(acc[r][1]);
                o.z = f2bf(acc[r][2]); o.w = f2bf(acc[r][3]);
                *reinterpret_cast<ushort4*>(&Cb[(size_t)row * Nc + bn + (tx << 2)]) = o;
            }
        }
        __syncthreads();
        if (tid < 64) {
            float s = 0.f, dd = 0.f;
            #pragma unroll
            for (int k = 0; k < 16; k++) { s += red_s[tid][k]; dd += red_d[tid][k]; }
            int row = bm + tid;
            if (row < M) {
                int hh = bn >> 6;
                a_src[(size_t)row * H + hh] = s;
                a_dst[(size_t)row * H + hh] = dd;
            }
        }
    } else {
        #pragma unroll
        for (int r = 0; r < 4; r++) {
            int row = bm + (ty << 2) + r;
            if (row < M) {
                float4 v;
                float4 bb = *reinterpret_cast<const float4*>(&bias[bn + (tx << 2)]);
                v.x = acc[r][0] + bb.x; v.y = acc[r][1] + bb.y;
                v.z = acc[r][2] + bb.z; v.w = acc[r][3] + bb.w;
                *reinterpret_cast<float4*>(&Cf[(size_t)row * Nc + bn + (tx << 2)]) = v;
            }
        }
    }
}

// ---------------- attention weights: w̃ = exp(e - m) per edge (unnormalized) ----------------
// Head-major wbuf[H][E]; per node also w̃self and rinv = 1/(sum + eps).
template<int H>
__global__ void k_attw(const float* __restrict__ asrc, const float* __restrict__ adst,
                       const int* __restrict__ startp, const int* __restrict__ deg,
                       const int* __restrict__ col,
                       float* __restrict__ wbuf, float* __restrict__ wself,
                       float* __restrict__ rinv, int n, int Et)
{
    int wv = (blockIdx.x * blockDim.x + threadIdx.x) >> 6;
    int lane = threadIdx.x & 63;
    if (wv >= n) return;
    const int s0 = startp[wv], d = deg[wv];
    float ad[H], es[H], mx[H];
    #pragma unroll
    for (int h = 0; h < H; h++) {
        ad[h] = adst[wv * H + h];
        es[h] = lrelu(asrc[wv * H + h] + ad[h]);
        mx[h] = es[h];
    }
    for (int t = lane; t < d; t += 64) {
        int s = col[s0 + t];
        if constexpr (H == 4) {
            float4 a4 = *reinterpret_cast<const float4*>(&asrc[s * 4]);
            mx[0] = fmaxf(mx[0], lrelu(a4.x + ad[0]));
            mx[1] = fmaxf(mx[1], lrelu(a4.y + ad[1]));
            mx[2] = fmaxf(mx[2], lrelu(a4.z + ad[2]));
            mx[3] = fmaxf(mx[3], lrelu(a4.w + ad[3]));
        } else {
            mx[0] = fmaxf(mx[0], lrelu(asrc[s] + ad[0]));
        }
    }
    #pragma unroll
    for (int h = 0; h < H; h++)
        #pragma unroll
        for (int off = 32; off; off >>= 1)
            mx[h] = fmaxf(mx[h], __shfl_xor(mx[h], off));
    float sm[H];
    #pragma unroll
    for (int h = 0; h < H; h++) sm[h] = (lane == 0) ? __expf(es[h] - mx[h]) : 0.f;
    for (int t = lane; t < d; t += 64) {
        int s = col[s0 + t];
        if constexpr (H == 4) {
            float4 a4 = *reinterpret_cast<const float4*>(&asrc[s * 4]);
            float e0 = lrelu(a4.x + ad[0]), e1 = lrelu(a4.y + ad[1]);
            float e2 = lrelu(a4.z + ad[2]), e3 = lrelu(a4.w + ad[3]);
            float w0 = __expf(e0 - mx[0]), w1 = __expf(e1 - mx[1]);
            float w2 = __expf(e2 - mx[2]), w3 = __expf(e3 - mx[3]);
            sm[0] += w0; sm[1] += w1; sm[2] += w2; sm[3] += w3;
            wbuf[0 * (size_t)Et + s0 + t] = w0;
            wbuf[1 * (size_t)Et + s0 + t] = w1;
            wbuf[2 * (size_t)Et + s0 + t] = w2;
            wbuf[3 * (size_t)Et + s0 + t] = w3;
        } else {
            float w = __expf(lrelu(asrc[s] + ad[0]) - mx[0]);
            sm[0] += w;
            wbuf[s0 + t] = w;
        }
    }
    #pragma unroll
    for (int h = 0; h < H; h++)
        #pragma unroll
        for (int off = 32; off; off >>= 1)
            sm[h] += __shfl_xor(sm[h], off);
    if (lane == 0) {
        #pragma unroll
        for (int h = 0; h < H; h++) {
            rinv[wv * H + h]  = 1.f / (sm[h] + 1e-16f);
            wself[wv * H + h] = __expf(es[h] - mx[h]);
        }
    }
}

// ---------------- weighted gather-accumulate, H=4 (lane owns 4 ch of 256) ----------------
__global__ void k_aggw4(const unsigned short* __restrict__ hb,
                        const float* __restrict__ wbuf, const float* __restrict__ wself,
                        const float* __restrict__ rinv,
                        const int* __restrict__ startp, const int* __restrict__ deg,
                        const int* __restrict__ col, const float* __restrict__ bias,
                        float* __restrict__ out, int n, int Et)
{
    int wv = (blockIdx.x * blockDim.x + threadIdx.x) >> 6;
    int lane = threadIdx.x & 63;
    if (wv >= n) return;
    const int s0 = startp[wv], d = deg[wv];
    const int hs = lane >> 4;
    const size_t cb = (size_t)wv * 256 + (lane << 2);
    const float wsf = wself[wv * 4 + hs];
    const float rv  = rinv[wv * 4 + hs];
    ushort4 v = *reinterpret_cast<const ushort4*>(&hb[cb]);
    float a0 = wsf * bf2f(v.x), a1 = wsf * bf2f(v.y);
    float a2 = wsf * bf2f(v.z), a3 = wsf * bf2f(v.w);
    const float* wrow = wbuf + (size_t)hs * Et + s0;
    const int* crow = col + s0;
    int t = 0;
    for (; t + 4 <= d; t += 4) {
        int sA = crow[t], sB = crow[t + 1], sC = crow[t + 2], sD = crow[t + 3];
        float wA = wrow[t], wB = wrow[t + 1], wC = wrow[t + 2], wD = wrow[t + 3];
        ushort4 uA = *reinterpret_cast<const ushort4*>(&hb[(size_t)sA * 256 + (lane << 2)]);
        ushort4 uB = *reinterpret_cast<const ushort4*>(&hb[(size_t)sB * 256 + (lane << 2)]);
        ushort4 uC = *reinterpret_cast<const ushort4*>(&hb[(size_t)sC * 256 + (lane << 2)]);
        ushort4 uD = *reinterpret_cast<const ushort4*>(&hb[(size_t)sD * 256 + (lane << 2)]);
        a0 += wA * bf2f(uA.x) + wB * bf2f(uB.x) + wC * bf2f(uC.x) + wD * bf2f(uD.x);
        a1 += wA * bf2f(uA.y) + wB * bf2f(uB.y) + wC * bf2f(uC.y) + wD * bf2f(uD.y);
        a2 += wA * bf2f(uA.z) + wB * bf2f(uB.z) + wC * bf2f(uC.z) + wD * bf2f(uD.z);
        a3 += wA * bf2f(uA.w) + wB * bf2f(uB.w) + wC * bf2f(uC.w) + wD * bf2f(uD.w);
    }
    for (; t < d; t++) {
        int s = crow[t];
        float w = wrow[t];
        ushort4 u = *reinterpret_cast<const ushort4*>(&hb[(size_t)s * 256 + (lane << 2)]);
        a0 += w * bf2f(u.x); a1 += w * bf2f(u.y);
        a2 += w * bf2f(u.z); a3 += w * bf2f(u.w);
    }
    const float4 bv = *reinterpret_cast<const float4*>(&bias[lane << 2]);
    float4 o;
    o.x = a0 * rv + bv.x; o.y = a1 * rv + bv.y;
    o.z = a2 * rv + bv.z; o.w = a3 * rv + bv.w;
    *reinterpret_cast<float4*>(&out[cb]) = o;
}

// ---------------- weighted gather-accumulate, H=1 (4 edge-groups x 16 lanes) ----------------
__global__ void k_aggw1(const unsigned short* __restrict__ hb,
                        const float* __restrict__ wbuf, const float* __restrict__ wself,
                        const float* __restrict__ rinv,
                        const int* __restrict__ startp, const int* __restrict__ deg,
                        const int* __restrict__ col, const float* __restrict__ bias,
                        float* __restrict__ out, int n)
{
    int wv = (blockIdx.x * blockDim.x + threadIdx.x) >> 6;
    int lane = threadIdx.x & 63;
    if (wv >= n) return;
    const int s0 = startp[wv], d = deg[wv];
    const int g = lane >> 4, l16 = lane & 15;
    const size_t cb = (size_t)wv * 64 + (l16 << 2);
    float a0 = 0.f, a1 = 0.f, a2 = 0.f, a3 = 0.f;
    if (g == 0) {
        float w = wself[wv];
        ushort4 v = *reinterpret_cast<const ushort4*>(&hb[cb]);
        a0 = w * bf2f(v.x); a1 = w * bf2f(v.y);
        a2 = w * bf2f(v.z); a3 = w * bf2f(v.w);
    }
    #pragma unroll 2
    for (int t = g; t < d; t += 4) {
        int s = col[s0 + t];
        float w = wbuf[s0 + t];
        ushort4 u = *reinterpret_cast<const ushort4*>(&hb[(size_t)s * 64 + (l16 << 2)]);
        a0 += w * bf2f(u.x); a1 += w * bf2f(u.y);
        a2 += w * bf2f(u.z); a3 += w * bf2f(u.w);
    }
    #pragma unroll
    for (int off = 16; off <= 32; off <<= 1) {
        a0 += __shfl_xor(a0, off); a1 += __shfl_xor(a1, off);
        a2 += __shfl_xor(a2, off); a3 += __shfl_xor(a3, off);
    }
    if (g == 0) {
        float rv = rinv[wv];
        float4 bv = *reinterpret_cast<const float4*>(&bias[l16 << 2]);
        float4 o;
        o.x = a0 * rv + bv.x; o.y = a1 * rv + bv.y;
        o.z = a2 * rv + bv.z; o.w = a3 * rv + bv.w;
        *reinterpret_cast<float4*>(&out[cb]) = o;
    }
}

// ---------------- BatchNorm stats + finalize ----------------
__global__ void k_bnstats(const float* __restrict__ x, int n, int c, float* __restrict__ accum)
{
    const int tid = threadIdx.x;
    const int colv = tid % c;
    const int rsub = tid / c;
    const int rpb = 256 / c;
    float s = 0.f, s2 = 0.f;
    for (int r = blockIdx.x * rpb + rsub; r < n; r += gridDim.x * rpb) {
        float v = x[(size_t)r * c + colv];
        s += v; s2 += v * v;
    }
    __shared__ float ls[256], ls2[256];
    ls[tid] = s; ls2[tid] = s2;
    __syncthreads();
    if (rsub == 0) {
        for (int k = 1; k < rpb; k++) { s += ls[k * c + colv]; s2 += ls2[k * c + colv]; }
        atomicAdd(&accum[colv], s);
        atomicAdd(&accum[c + colv], s2);
    }
}

__global__ void k_bnfinal(float* __restrict__ st, int c, float invN)
{
    int t = threadIdx.x;
    if (t < c) {
        float m = st[t] * invN;
        float var = st[c + t] * invN - m * m;
        st[2 * c + t] = m;
        st[3 * c + t] = rsqrtf(var + EPS_BN);
    }
}

// ---------------- final head ----------------
__global__ void k_head(const float* __restrict__ h, const float* __restrict__ st,
                       const float* __restrict__ lw2, const float* __restrict__ lb2,
                       float* __restrict__ out, int n)
{
    int wv = (blockIdx.x * blockDim.x + threadIdx.x) >> 6;
    int lane = threadIdx.x & 63;
    if (wv >= n) return;
    float m  = st[128 + lane];
    float rs = st[192 + lane];
    float v = fmaxf((h[(size_t)wv * 64 + lane] - m) * rs, 0.f);
    float c0 = v * lw2[lane * 2 + 0];
    float c1 = v * lw2[lane * 2 + 1];
    #pragma unroll
    for (int off = 32; off; off >>= 1) {
        c0 += __shfl_xor(c0, off);
        c1 += __shfl_xor(c1, off);
    }
    if (lane == 0) {
        out[wv * 2 + 0] = c0 + lb2[0];
        out[wv * 2 + 1] = c1 + lb2[1];
    }
}

extern "C" void kernel_launch(void* const* d_in, const int* in_sizes, int n_in,
                              void* d_out, int out_size, void* d_ws, size_t ws_size,
                              hipStream_t stream)
{
    const float* x   = (const float*)d_in[0];
    const int*   ei  = (const int*)d_in[1];
    const float* W0  = (const float*)d_in[2];
    const float* as0 = (const float*)d_in[3];
    const float* ad0 = (const float*)d_in[4];
    const float* b0  = (const float*)d_in[5];
    const float* W1  = (const float*)d_in[6];
    const float* as1 = (const float*)d_in[7];
    const float* ad1 = (const float*)d_in[8];
    const float* b1  = (const float*)d_in[9];
    const float* W2  = (const float*)d_in[10];
    const float* as2 = (const float*)d_in[11];
    const float* ad2 = (const float*)d_in[12];
    const float* b2  = (const float*)d_in[13];
    const float* lw1 = (const float*)d_in[14];
    const float* lb1 = (const float*)d_in[15];
    const float* lw2 = (const float*)d_in[16];
    const float* lb2 = (const float*)d_in[17];
    float* out = (float*)d_out;

    const int n = in_sizes[0] / F_IN;   // 50000
    const int e = in_sizes[1] / 2;      // 800000

    char* ws = (char*)d_ws;
    size_t off = 0;
    auto alloc = [&](size_t bytes) -> void* {
        void* p = ws + off;
        off += (bytes + 255) & ~(size_t)255;
        return p;
    };
    float* B            = (float*)alloc((size_t)n * 256 * 4);           // agg outputs
    unsigned short* Hb  = (unsigned short*)alloc((size_t)n * 256 * 2);  // bf16 gather buf
    float* g3           = (float*)Hb;                                   // alias (Hb dead by MLP)
    float* a_src = (float*)alloc((size_t)n * 4 * 4);
    float* a_dst = (float*)alloc((size_t)n * 4 * 4);
    float* wself = (float*)alloc((size_t)n * 4 * 4);
    float* rinv  = (float*)alloc((size_t)n * 4 * 4);
    float* stats = (float*)alloc(4 * 1024 * 4);
    int* deg    = (int*)alloc((size_t)n * 4);
    int* fill   = (int*)alloc((size_t)n * 4);
    int* startp = (int*)alloc((size_t)n * 4);
    int* cursor = (int*)alloc(256);
    int* col    = (int*)alloc((size_t)e * 4);
    float* wbuf = (float*)alloc((size_t)4 * e * 4);                     // head-major [H][E]

    float* st0 = stats;
    float* st1 = stats + 1024;
    float* st2 = stats + 2048;
    float* st3 = stats + 3072;
    const float invN = 1.f / (float)n;

    hipMemsetAsync(stats, 0, 4 * 1024 * 4, stream);
    hipMemsetAsync(deg, 0, (size_t)n * 4, stream);
    hipMemsetAsync(fill, 0, (size_t)n * 4, stream);
    hipMemsetAsync(cursor, 0, 4, stream);

    const int tpb = 256;
    k_deg<<<(e + tpb - 1) / tpb, tpb, 0, stream>>>(ei, e, deg);
    k_offsets<<<(n + tpb - 1) / tpb, tpb, 0, stream>>>(deg, startp, cursor, n);
    k_fill<<<(e + tpb - 1) / tpb, tpb, 0, stream>>>(ei, e, startp, fill, col);

    const int wgrid = (n + 3) / 4;
    const int rowTiles = (n + 63) / 64;

    // Layer 0: GAT 128 -> 4x64
    k_gemm<false, true><<<dim3(rowTiles, 4), 256, 0, stream>>>(
        x, W0, nullptr, nullptr, nullptr, as0, ad0, a_src, a_dst, 4,
        nullptr, Hb, n, 128, 256);
    k_attw<4><<<wgrid, 256, 0, stream>>>(a_src, a_dst, startp, deg, col, wbuf, wself, rinv, n, e);
    k_aggw4<<<wgrid, 256, 0, stream>>>(Hb, wbuf, wself, rinv, startp, deg, col, b0, B, n, e);
    k_bnstats<<<256, 256, 0, stream>>>(B, n, 256, st0);
    k_bnfinal<<<1, 256, 0, stream>>>(st0, 256, invN);

    // Layer 1: GAT 256 -> 64 (BN+ReLU fused into A-load)
    k_gemm<true, true><<<dim3(rowTiles, 1), 256, 0, stream>>>(
        B, W1, nullptr, st0 + 512, st0 + 768, as1, ad1, a_src, a_dst, 1,
        nullptr, Hb, n, 256, 64);
    k_attw<1><<<wgrid, 256, 0, stream>>>(a_src, a_dst, startp, deg, col, wbuf, wself, rinv, n, e);
    k_aggw1<<<wgrid, 256, 0, stream>>>(Hb, wbuf, wself, rinv, startp, deg, col, b1, B, n);
    k_bnstats<<<256, 256, 0, stream>>>(B, n, 64, st1);
    k_bnfinal<<<1, 256, 0, stream>>>(st1, 64, invN);

    // Layer 2: GAT 64 -> 64
    k_gemm<true, true><<<dim3(rowTiles, 1), 256, 0, stream>>>(
        B, W2, nullptr, st1 + 128, st1 + 192, as2, ad2, a_src, a_dst, 1,
        nullptr, Hb, n, 64, 64);
    k_attw<1><<<wgrid, 256, 0, stream>>>(a_src, a_dst, startp, deg, col, wbuf, wself, rinv, n, e);
    k_aggw1<<<wgrid, 256, 0, stream>>>(Hb, wbuf, wself, rinv, startp, deg, col, b2, B, n);
    k_bnstats<<<256, 256, 0, stream>>>(B, n, 64, st2);
    k_bnfinal<<<1, 256, 0, stream>>>(st2, 64, invN);

    // MLP: relu(bn(o2)) @ lw1 + lb1
    k_gemm<true, false><<<dim3(rowTiles, 1), 256, 0, stream>>>(
        B, lw1, lb1, st2 + 128, st2 + 192, nullptr, nullptr, nullptr, nullptr, 1,
        g3, nullptr, n, 64, 64);
    k_bnstats<<<256, 256, 0, stream>>>(g3, n, 64, st3);
    k_bnfinal<<<1, 256, 0, stream>>>(st3, 64, invN);

    // head: relu(bn(g3)) @ lw2 + lb2
    k_head<<<wgrid, 256, 0, stream>>>(g3, st3, lw2, lb2, out, n);
}

// Round 4
// 422.504 us; speedup vs baseline: 1.7835x; 1.2497x over previous
//
#include <hip/hip_runtime.h>

#define F_IN 128
#define EPS_BN 1e-5f

typedef __attribute__((ext_vector_type(8))) short short8v;
typedef __attribute__((ext_vector_type(4))) float f32x4;

__device__ __forceinline__ float lrelu(float x) { return x >= 0.f ? x : 0.2f * x; }
__device__ __forceinline__ unsigned short f2bf(float f) {
    unsigned int u = __float_as_uint(f);
    u += 0x7FFFu + ((u >> 16) & 1u);
    return (unsigned short)(u >> 16);
}
__device__ __forceinline__ float bf2f(unsigned short s) {
    return __uint_as_float(((unsigned int)s) << 16);
}

// ---------------- CSR build ----------------
__global__ void k_deg(const int* __restrict__ ei, int e, int* __restrict__ deg) {
    int t = blockIdx.x * blockDim.x + threadIdx.x;
    if (t < e) atomicAdd(&deg[ei[e + t]], 1);   // ei[E..2E) = dst
}

__global__ void k_offsets(const int* __restrict__ deg, int* __restrict__ startp,
                          int* __restrict__ cursor, int n) {
    int t = blockIdx.x * blockDim.x + threadIdx.x;
    int lane = threadIdx.x & 63;
    int d = (t < n) ? deg[t] : 0;
    int pre = d;
    #pragma unroll
    for (int off = 1; off < 64; off <<= 1) {
        int u = __shfl_up(pre, off);
        if (lane >= off) pre += u;
    }
    int total = __shfl(pre, 63);
    int base = 0;
    if (lane == 0) base = atomicAdd(cursor, total);
    base = __shfl(base, 0);
    if (t < n) startp[t] = base + pre - d;
}

__global__ void k_fill(const int* __restrict__ ei, int e, const int* __restrict__ startp,
                       int* __restrict__ fill, int* __restrict__ col) {
    int t = blockIdx.x * blockDim.x + threadIdx.x;
    if (t < e) {
        int s = ei[t];
        int dd = ei[e + t];
        int p = startp[dd] + atomicAdd(&fill[dd], 1);
        col[p] = s;
    }
}

// ---------------- weight prep: Wt[n][k] = bf16(W[k][n]) ----------------
__global__ void k_wprep(const float* __restrict__ W, unsigned short* __restrict__ Wt,
                        int K, int Nc) {
    int t = blockIdx.x * blockDim.x + threadIdx.x;
    if (t < K * Nc) {
        int nn = t / K, kk = t - nn * K;
        Wt[t] = f2bf(W[(size_t)kk * Nc + nn]);
    }
}

// ---------------- bf16 MFMA GEMM: C[M,Nc] = f(A)[M,K] @ W[K,Nc] ----------------
// f = identity or BN-normalize+ReLU. Wt is bf16 [Nc][K] (pre-transposed).
// ATT: write C as bf16 gather buffer + compute per-row attention dots (head = bn>>6).
// !ATT: write C as fp32 + bias.
template<bool BN, bool ATT>
__global__ __launch_bounds__(256) void k_gemm(
    const float* __restrict__ A, const unsigned short* __restrict__ Wt,
    const float* __restrict__ bias,
    const float* __restrict__ mu, const float* __restrict__ rstd,
    const float* __restrict__ att_s, const float* __restrict__ att_d,
    float* __restrict__ a_src, float* __restrict__ a_dst, int H,
    float* __restrict__ Cf, unsigned short* __restrict__ Cb,
    int M, int K, int Nc)
{
    __shared__ unsigned short As[64 * 40];   // [m][k], row stride 40 (pad 8)
    __shared__ unsigned short Bs[64 * 40];   // [n][k]
    const int tid = threadIdx.x;
    const int w = tid >> 6, lane = tid & 63;
    const int l15 = lane & 15, g = lane >> 4;
    const int bm = blockIdx.x * 64, bn = blockIdx.y * 64;
    const int srow = tid >> 2;         // 0..63
    const int skq  = (tid & 3) << 3;   // 0,8,16,24

    f32x4 acc[4];
    #pragma unroll
    for (int nt = 0; nt < 4; nt++) acc[nt] = (f32x4){0.f, 0.f, 0.f, 0.f};

    for (int k0 = 0; k0 < K; k0 += 32) {
        // ---- stage A (fp32 -> optional BN/ReLU -> bf16) ----
        short8v a8;
        if (bm + srow < M) {
            const float* ap = &A[(size_t)(bm + srow) * K + k0 + skq];
            float4 v0 = *reinterpret_cast<const float4*>(ap);
            float4 v1 = *reinterpret_cast<const float4*>(ap + 4);
            if constexpr (BN) {
                float4 m0 = *reinterpret_cast<const float4*>(&mu[k0 + skq]);
                float4 m1 = *reinterpret_cast<const float4*>(&mu[k0 + skq + 4]);
                float4 r0 = *reinterpret_cast<const float4*>(&rstd[k0 + skq]);
                float4 r1 = *reinterpret_cast<const float4*>(&rstd[k0 + skq + 4]);
                v0.x = fmaxf((v0.x - m0.x) * r0.x, 0.f);
                v0.y = fmaxf((v0.y - m0.y) * r0.y, 0.f);
                v0.z = fmaxf((v0.z - m0.z) * r0.z, 0.f);
                v0.w = fmaxf((v0.w - m0.w) * r0.w, 0.f);
                v1.x = fmaxf((v1.x - m1.x) * r1.x, 0.f);
                v1.y = fmaxf((v1.y - m1.y) * r1.y, 0.f);
                v1.z = fmaxf((v1.z - m1.z) * r1.z, 0.f);
                v1.w = fmaxf((v1.w - m1.w) * r1.w, 0.f);
            }
            a8[0] = (short)f2bf(v0.x); a8[1] = (short)f2bf(v0.y);
            a8[2] = (short)f2bf(v0.z); a8[3] = (short)f2bf(v0.w);
            a8[4] = (short)f2bf(v1.x); a8[5] = (short)f2bf(v1.y);
            a8[6] = (short)f2bf(v1.z); a8[7] = (short)f2bf(v1.w);
        } else {
            a8 = (short8v){0,0,0,0,0,0,0,0};
        }
        // ---- stage B from pre-transposed bf16 weights ----
        short8v b8 = *reinterpret_cast<const short8v*>(&Wt[(size_t)(bn + srow) * K + k0 + skq]);
        __syncthreads();
        *reinterpret_cast<short8v*>(&As[srow * 40 + skq]) = a8;
        *reinterpret_cast<short8v*>(&Bs[srow * 40 + skq]) = b8;
        __syncthreads();
        // ---- MFMA: wave w owns rows w*16..+15, all 4 n-tiles ----
        short8v af = *reinterpret_cast<const short8v*>(&As[(w * 16 + l15) * 40 + g * 8]);
        #pragma unroll
        for (int nt = 0; nt < 4; nt++) {
            short8v bf = *reinterpret_cast<const short8v*>(&Bs[(nt * 16 + l15) * 40 + g * 8]);
            acc[nt] = __builtin_amdgcn_mfma_f32_16x16x32_bf16(af, bf, acc[nt], 0, 0, 0);
        }
    }

    if constexpr (ATT) {
        float wsv[4], wdv[4];
        #pragma unroll
        for (int nt = 0; nt < 4; nt++) {
            wsv[nt] = att_s[bn + nt * 16 + l15];
            wdv[nt] = att_d[bn + nt * 16 + l15];
        }
        #pragma unroll
        for (int reg = 0; reg < 4; reg++) {
            int row = bm + w * 16 + g * 4 + reg;
            float ps = 0.f, pd = 0.f;
            #pragma unroll
            for (int nt = 0; nt < 4; nt++) {
                float c = acc[nt][reg];
                ps += c * wsv[nt];
                pd += c * wdv[nt];
                if (row < M)
                    Cb[(size_t)row * Nc + bn + nt * 16 + l15] = f2bf(c);
            }
            #pragma unroll
            for (int off = 1; off < 16; off <<= 1) {
                ps += __shfl_xor(ps, off);
                pd += __shfl_xor(pd, off);
            }
            if (l15 == 0 && row < M) {
                int hh = bn >> 6;
                a_src[(size_t)row * H + hh] = ps;
                a_dst[(size_t)row * H + hh] = pd;
            }
        }
    } else {
        #pragma unroll
        for (int reg = 0; reg < 4; reg++) {
            int row = bm + w * 16 + g * 4 + reg;
            if (row < M) {
                #pragma unroll
                for (int nt = 0; nt < 4; nt++)
                    Cf[(size_t)row * Nc + bn + nt * 16 + l15] =
                        acc[nt][reg] + bias[bn + nt * 16 + l15];
            }
        }
    }
}

// ---------------- fused softmax aggregation, H=4 (no max-shift, branch-free) ----------------
__global__ void k_agg4f(const unsigned short* __restrict__ hb,
                        const float* __restrict__ asrc, const float* __restrict__ adst,
                        const int* __restrict__ startp, const int* __restrict__ deg,
                        const int* __restrict__ col, const float* __restrict__ bias,
                        float* __restrict__ out, int n)
{
    int wv = (blockIdx.x * blockDim.x + threadIdx.x) >> 6;
    int lane = threadIdx.x & 63;
    if (wv >= n) return;
    const int s0 = startp[wv], d = deg[wv];
    const int hs = lane >> 4;
    const float adh = adst[wv * 4 + hs];
    const float ws = __expf(lrelu(asrc[wv * 4 + hs] + adh));
    const size_t cb = (size_t)wv * 256 + (lane << 2);
    ushort4 v = *reinterpret_cast<const ushort4*>(&hb[cb]);
    float a0 = ws * bf2f(v.x), a1 = ws * bf2f(v.y);
    float a2 = ws * bf2f(v.z), a3 = ws * bf2f(v.w);
    float sm = ws;
    const int* crow = col + s0;
    int t = 0;
    for (; t + 4 <= d; t += 4) {
        int sA = crow[t], sB = crow[t + 1], sC = crow[t + 2], sD = crow[t + 3];
        float wA = __expf(lrelu(asrc[sA * 4 + hs] + adh));
        float wB = __expf(lrelu(asrc[sB * 4 + hs] + adh));
        float wC = __expf(lrelu(asrc[sC * 4 + hs] + adh));
        float wD = __expf(lrelu(asrc[sD * 4 + hs] + adh));
        ushort4 uA = *reinterpret_cast<const ushort4*>(&hb[(size_t)sA * 256 + (lane << 2)]);
        ushort4 uB = *reinterpret_cast<const ushort4*>(&hb[(size_t)sB * 256 + (lane << 2)]);
        ushort4 uC = *reinterpret_cast<const ushort4*>(&hb[(size_t)sC * 256 + (lane << 2)]);
        ushort4 uD = *reinterpret_cast<const ushort4*>(&hb[(size_t)sD * 256 + (lane << 2)]);
        sm += wA + wB + wC + wD;
        a0 += wA * bf2f(uA.x) + wB * bf2f(uB.x) + wC * bf2f(uC.x) + wD * bf2f(uD.x);
        a1 += wA * bf2f(uA.y) + wB * bf2f(uB.y) + wC * bf2f(uC.y) + wD * bf2f(uD.y);
        a2 += wA * bf2f(uA.z) + wB * bf2f(uB.z) + wC * bf2f(uC.z) + wD * bf2f(uD.z);
        a3 += wA * bf2f(uA.w) + wB * bf2f(uB.w) + wC * bf2f(uC.w) + wD * bf2f(uD.w);
    }
    for (; t < d; t++) {
        int s = crow[t];
        float w = __expf(lrelu(asrc[s * 4 + hs] + adh));
        ushort4 u = *reinterpret_cast<const ushort4*>(&hb[(size_t)s * 256 + (lane << 2)]);
        sm += w;
        a0 += w * bf2f(u.x); a1 += w * bf2f(u.y);
        a2 += w * bf2f(u.z); a3 += w * bf2f(u.w);
    }
    float rv = 1.f / (sm + 1e-16f);
    const float4 bv = *reinterpret_cast<const float4*>(&bias[lane << 2]);
    float4 o;
    o.x = a0 * rv + bv.x; o.y = a1 * rv + bv.y;
    o.z = a2 * rv + bv.z; o.w = a3 * rv + bv.w;
    *reinterpret_cast<float4*>(&out[cb]) = o;
}

// ---------------- fused softmax aggregation, H=1 (4 edge-groups x 16 lanes) ----------------
__global__ void k_agg1f(const unsigned short* __restrict__ hb,
                        const float* __restrict__ asrc, const float* __restrict__ adst,
                        const int* __restrict__ startp, const int* __restrict__ deg,
                        const int* __restrict__ col, const float* __restrict__ bias,
                        float* __restrict__ out, int n)
{
    int wv = (blockIdx.x * blockDim.x + threadIdx.x) >> 6;
    int lane = threadIdx.x & 63;
    if (wv >= n) return;
    const int s0 = startp[wv], d = deg[wv];
    const int g = lane >> 4, l16 = lane & 15;
    const float adv = adst[wv];
    const size_t cb = (size_t)wv * 64 + (l16 << 2);
    float a0 = 0.f, a1 = 0.f, a2 = 0.f, a3 = 0.f, sm = 0.f;
    if (g == 0) {
        float w = __expf(lrelu(asrc[wv] + adv));
        ushort4 v = *reinterpret_cast<const ushort4*>(&hb[cb]);
        a0 = w * bf2f(v.x); a1 = w * bf2f(v.y);
        a2 = w * bf2f(v.z); a3 = w * bf2f(v.w);
        sm = w;
    }
    #pragma unroll 2
    for (int t = g; t < d; t += 4) {
        int s = col[s0 + t];
        float w = __expf(lrelu(asrc[s] + adv));
        ushort4 u = *reinterpret_cast<const ushort4*>(&hb[(size_t)s * 64 + (l16 << 2)]);
        sm += w;
        a0 += w * bf2f(u.x); a1 += w * bf2f(u.y);
        a2 += w * bf2f(u.z); a3 += w * bf2f(u.w);
    }
    #pragma unroll
    for (int off = 16; off <= 32; off <<= 1) {
        a0 += __shfl_xor(a0, off); a1 += __shfl_xor(a1, off);
        a2 += __shfl_xor(a2, off); a3 += __shfl_xor(a3, off);
        sm += __shfl_xor(sm, off);
    }
    if (g == 0) {
        float rv = 1.f / (sm + 1e-16f);
        float4 bv = *reinterpret_cast<const float4*>(&bias[l16 << 2]);
        float4 o;
        o.x = a0 * rv + bv.x; o.y = a1 * rv + bv.y;
        o.z = a2 * rv + bv.z; o.w = a3 * rv + bv.w;
        *reinterpret_cast<float4*>(&out[cb]) = o;
    }
}

// ---------------- BatchNorm stats + finalize ----------------
__global__ void k_bnstats(const float* __restrict__ x, int n, int c, float* __restrict__ accum)
{
    const int tid = threadIdx.x;
    const int colv = tid % c;
    const int rsub = tid / c;
    const int rpb = 256 / c;
    float s = 0.f, s2 = 0.f;
    for (int r = blockIdx.x * rpb + rsub; r < n; r += gridDim.x * rpb) {
        float v = x[(size_t)r * c + colv];
        s += v; s2 += v * v;
    }
    __shared__ float ls[256], ls2[256];
    ls[tid] = s; ls2[tid] = s2;
    __syncthreads();
    if (rsub == 0) {
        for (int k = 1; k < rpb; k++) { s += ls[k * c + colv]; s2 += ls2[k * c + colv]; }
        atomicAdd(&accum[colv], s);
        atomicAdd(&accum[c + colv], s2);
    }
}

__global__ void k_bnfinal(float* __restrict__ st, int c, float invN)
{
    int t = threadIdx.x;
    if (t < c) {
        float m = st[t] * invN;
        float var = st[c + t] * invN - m * m;
        st[2 * c + t] = m;
        st[3 * c + t] = rsqrtf(var + EPS_BN);
    }
}

// ---------------- final head ----------------
__global__ void k_head(const float* __restrict__ h, const float* __restrict__ st,
                       const float* __restrict__ lw2, const float* __restrict__ lb2,
                       float* __restrict__ out, int n)
{
    int wv = (blockIdx.x * blockDim.x + threadIdx.x) >> 6;
    int lane = threadIdx.x & 63;
    if (wv >= n) return;
    float m  = st[128 + lane];
    float rs = st[192 + lane];
    float v = fmaxf((h[(size_t)wv * 64 + lane] - m) * rs, 0.f);
    float c0 = v * lw2[lane * 2 + 0];
    float c1 = v * lw2[lane * 2 + 1];
    #pragma unroll
    for (int off = 32; off; off >>= 1) {
        c0 += __shfl_xor(c0, off);
        c1 += __shfl_xor(c1, off);
    }
    if (lane == 0) {
        out[wv * 2 + 0] = c0 + lb2[0];
        out[wv * 2 + 1] = c1 + lb2[1];
    }
}

extern "C" void kernel_launch(void* const* d_in, const int* in_sizes, int n_in,
                              void* d_out, int out_size, void* d_ws, size_t ws_size,
                              hipStream_t stream)
{
    const float* x   = (const float*)d_in[0];
    const int*   ei  = (const int*)d_in[1];
    const float* W0  = (const float*)d_in[2];
    const float* as0 = (const float*)d_in[3];
    const float* ad0 = (const float*)d_in[4];
    const float* b0  = (const float*)d_in[5];
    const float* W1  = (const float*)d_in[6];
    const float* as1 = (const float*)d_in[7];
    const float* ad1 = (const float*)d_in[8];
    const float* b1  = (const float*)d_in[9];
    const float* W2  = (const float*)d_in[10];
    const float* as2 = (const float*)d_in[11];
    const float* ad2 = (const float*)d_in[12];
    const float* b2  = (const float*)d_in[13];
    const float* lw1 = (const float*)d_in[14];
    const float* lb1 = (const float*)d_in[15];
    const float* lw2 = (const float*)d_in[16];
    const float* lb2 = (const float*)d_in[17];
    float* out = (float*)d_out;

    const int n = in_sizes[0] / F_IN;   // 50000
    const int e = in_sizes[1] / 2;      // 800000

    char* ws = (char*)d_ws;
    size_t off = 0;
    auto alloc = [&](size_t bytes) -> void* {
        void* p = ws + off;
        off += (bytes + 255) & ~(size_t)255;
        return p;
    };
    float* B            = (float*)alloc((size_t)n * 256 * 4);           // agg outputs
    unsigned short* Hb  = (unsigned short*)alloc((size_t)n * 256 * 2);  // bf16 gather buf
    float* g3           = (float*)Hb;                                   // alias (Hb dead by MLP)
    float* a_src = (float*)alloc((size_t)n * 4 * 4);
    float* a_dst = (float*)alloc((size_t)n * 4 * 4);
    float* stats = (float*)alloc(4 * 1024 * 4);
    int* deg    = (int*)alloc((size_t)n * 4);
    int* fill   = (int*)alloc((size_t)n * 4);
    int* startp = (int*)alloc((size_t)n * 4);
    int* cursor = (int*)alloc(256);
    int* col    = (int*)alloc((size_t)e * 4);
    unsigned short* Wt0 = (unsigned short*)alloc(256 * 128 * 2);
    unsigned short* Wt1 = (unsigned short*)alloc(64 * 256 * 2);
    unsigned short* Wt2 = (unsigned short*)alloc(64 * 64 * 2);
    unsigned short* Wtm = (unsigned short*)alloc(64 * 64 * 2);

    float* st0 = stats;
    float* st1 = stats + 1024;
    float* st2 = stats + 2048;
    float* st3 = stats + 3072;
    const float invN = 1.f / (float)n;

    hipMemsetAsync(stats, 0, 4 * 1024 * 4, stream);
    hipMemsetAsync(deg, 0, (size_t)n * 4, stream);
    hipMemsetAsync(fill, 0, (size_t)n * 4, stream);
    hipMemsetAsync(cursor, 0, 4, stream);

    const int tpb = 256;
    // weight prep (tiny, independent)
    k_wprep<<<(256 * 128 + 255) / 256, 256, 0, stream>>>(W0, Wt0, 128, 256);
    k_wprep<<<(64 * 256 + 255) / 256, 256, 0, stream>>>(W1, Wt1, 256, 64);
    k_wprep<<<(64 * 64 + 255) / 256, 256, 0, stream>>>(W2, Wt2, 64, 64);
    k_wprep<<<(64 * 64 + 255) / 256, 256, 0, stream>>>(lw1, Wtm, 64, 64);

    // CSR build
    k_deg<<<(e + tpb - 1) / tpb, tpb, 0, stream>>>(ei, e, deg);
    k_offsets<<<(n + tpb - 1) / tpb, tpb, 0, stream>>>(deg, startp, cursor, n);
    k_fill<<<(e + tpb - 1) / tpb, tpb, 0, stream>>>(ei, e, startp, fill, col);

    const int wgrid = (n + 3) / 4;
    const int rowTiles = (n + 63) / 64;

    // Layer 0: GAT 128 -> 4x64
    k_gemm<false, true><<<dim3(rowTiles, 4), 256, 0, stream>>>(
        x, Wt0, nullptr, nullptr, nullptr, as0, ad0, a_src, a_dst, 4,
        nullptr, Hb, n, 128, 256);
    k_agg4f<<<wgrid, 256, 0, stream>>>(Hb, a_src, a_dst, startp, deg, col, b0, B, n);
    k_bnstats<<<256, 256, 0, stream>>>(B, n, 256, st0);
    k_bnfinal<<<1, 256, 0, stream>>>(st0, 256, invN);

    // Layer 1: GAT 256 -> 64 (BN+ReLU fused into A-load)
    k_gemm<true, true><<<dim3(rowTiles, 1), 256, 0, stream>>>(
        B, Wt1, nullptr, st0 + 512, st0 + 768, as1, ad1, a_src, a_dst, 1,
        nullptr, Hb, n, 256, 64);
    k_agg1f<<<wgrid, 256, 0, stream>>>(Hb, a_src, a_dst, startp, deg, col, b1, B, n);
    k_bnstats<<<256, 256, 0, stream>>>(B, n, 64, st1);
    k_bnfinal<<<1, 256, 0, stream>>>(st1, 64, invN);

    // Layer 2: GAT 64 -> 64
    k_gemm<true, true><<<dim3(rowTiles, 1), 256, 0, stream>>>(
        B, Wt2, nullptr, st1 + 128, st1 + 192, as2, ad2, a_src, a_dst, 1,
        nullptr, Hb, n, 64, 64);
    k_agg1f<<<wgrid, 256, 0, stream>>>(Hb, a_src, a_dst, startp, deg, col, b2, B, n);
    k_bnstats<<<256, 256, 0, stream>>>(B, n, 64, st2);
    k_bnfinal<<<1, 256, 0, stream>>>(st2, 64, invN);

    // MLP: relu(bn(o2)) @ lw1 + lb1
    k_gemm<true, false><<<dim3(rowTiles, 1), 256, 0, stream>>>(
        B, Wtm, lb1, st2 + 128, st2 + 192, nullptr, nullptr, nullptr, nullptr, 1,
        g3, nullptr, n, 64, 64);
    k_bnstats<<<256, 256, 0, stream>>>(g3, n, 64, st3);
    k_bnfinal<<<1, 256, 0, stream>>>(st3, 64, invN);

    // head: relu(bn(g3)) @ lw2 + lb2
    k_head<<<wgrid, 256, 0, stream>>>(g3, st3, lw2, lb2, out, n);
}

// Round 5
// 380.465 us; speedup vs baseline: 1.9805x; 1.1105x over previous
//
#include <hip/hip_runtime.h>

#define F_IN 128
#define EPS_BN 1e-5f
#define NCOPY 8

typedef __attribute__((ext_vector_type(8))) short short8v;
typedef __attribute__((ext_vector_type(4))) float f32x4;

__device__ __forceinline__ float lrelu(float x) { return x >= 0.f ? x : 0.2f * x; }
__device__ __forceinline__ unsigned short f2bf(float f) {
    unsigned int u = __float_as_uint(f);
    u += 0x7FFFu + ((u >> 16) & 1u);
    return (unsigned short)(u >> 16);
}
__device__ __forceinline__ float bf2f(unsigned short s) {
    return __uint_as_float(((unsigned int)s) << 16);
}

// ---------------- CSR build ----------------
__global__ void k_deg(const int* __restrict__ ei, int e, int* __restrict__ deg) {
    int t = blockIdx.x * blockDim.x + threadIdx.x;
    if (t < e) atomicAdd(&deg[ei[e + t]], 1);   // ei[E..2E) = dst
}

__global__ void k_offsets(const int* __restrict__ deg, int* __restrict__ startp,
                          int* __restrict__ cursor, int n) {
    int t = blockIdx.x * blockDim.x + threadIdx.x;
    int lane = threadIdx.x & 63;
    int d = (t < n) ? deg[t] : 0;
    int pre = d;
    #pragma unroll
    for (int off = 1; off < 64; off <<= 1) {
        int u = __shfl_up(pre, off);
        if (lane >= off) pre += u;
    }
    int total = __shfl(pre, 63);
    int base = 0;
    if (lane == 0) base = atomicAdd(cursor, total);
    base = __shfl(base, 0);
    if (t < n) startp[t] = base + pre - d;
}

__global__ void k_fill(const int* __restrict__ ei, int e, const int* __restrict__ startp,
                       int* __restrict__ fill, int* __restrict__ col) {
    int t = blockIdx.x * blockDim.x + threadIdx.x;
    if (t < e) {
        int s = ei[t];
        int dd = ei[e + t];
        int p = startp[dd] + atomicAdd(&fill[dd], 1);
        col[p] = s;
    }
}

// ---------------- all weight preps in one launch: Wt[n][k] = bf16(W[k][n]) ----------------
__global__ void k_wprep_all(const float* __restrict__ W0, const float* __restrict__ W1,
                            const float* __restrict__ W2, const float* __restrict__ lw1,
                            unsigned short* __restrict__ Wt0, unsigned short* __restrict__ Wt1,
                            unsigned short* __restrict__ Wt2, unsigned short* __restrict__ Wtm)
{
    int t = blockIdx.x * blockDim.x + threadIdx.x;
    if (t < 32768) {               // W0: K=128, Nc=256
        int nn = t / 128, kk = t - nn * 128;
        Wt0[t] = f2bf(W0[(size_t)kk * 256 + nn]);
    } else if (t < 49152) {        // W1: K=256, Nc=64
        int u = t - 32768;
        int nn = u / 256, kk = u - nn * 256;
        Wt1[u] = f2bf(W1[(size_t)kk * 64 + nn]);
    } else if (t < 53248) {        // W2: K=64, Nc=64
        int u = t - 49152;
        int nn = u / 64, kk = u - nn * 64;
        Wt2[u] = f2bf(W2[(size_t)kk * 64 + nn]);
    } else if (t < 57344) {        // lw1: K=64, Nc=64
        int u = t - 53248;
        int nn = u / 64, kk = u - nn * 64;
        Wtm[u] = f2bf(lw1[(size_t)kk * 64 + nn]);
    }
}

// ---------------- bf16 MFMA GEMM: C[M,Nc] = f(A)[M,K] @ W[K,Nc] ----------------
// BN: A normalized+ReLU'd from raw 8-copy stats (copy stride 2K, sumsq at +K).
// ATT: write C as bf16 gather buffer + per-row attention dots (head = bn>>6).
// !ATT: write C fp32 + bias, and accumulate BN stats of C into ostats (8-copy).
template<bool BN, bool ATT>
__global__ __launch_bounds__(256) void k_gemm(
    const float* __restrict__ A, const unsigned short* __restrict__ Wt,
    const float* __restrict__ bias,
    const float* __restrict__ bnst, float invN,
    const float* __restrict__ att_s, const float* __restrict__ att_d,
    float* __restrict__ a_src, float* __restrict__ a_dst, int H,
    float* __restrict__ Cf, unsigned short* __restrict__ Cb,
    float* __restrict__ ostats,
    int M, int K, int Nc)
{
    __shared__ unsigned short As[64 * 40];
    __shared__ unsigned short Bs[64 * 40];
    __shared__ float muS[256], rsS[256];
    const int tid = threadIdx.x;
    const int w = tid >> 6, lane = tid & 63;
    const int l15 = lane & 15, g = lane >> 4;
    const int bm = blockIdx.x * 64, bn = blockIdx.y * 64;
    const int srow = tid >> 2;
    const int skq  = (tid & 3) << 3;

    if constexpr (BN) {
        if (tid < K) {
            float s = 0.f, s2 = 0.f;
            #pragma unroll
            for (int c = 0; c < NCOPY; c++) {
                s  += bnst[c * 2 * K + tid];
                s2 += bnst[c * 2 * K + K + tid];
            }
            float m = s * invN;
            float var = s2 * invN - m * m;
            muS[tid] = m;
            rsS[tid] = rsqrtf(var + EPS_BN);
        }
        __syncthreads();
    }

    f32x4 acc[4];
    #pragma unroll
    for (int nt = 0; nt < 4; nt++) acc[nt] = (f32x4){0.f, 0.f, 0.f, 0.f};

    for (int k0 = 0; k0 < K; k0 += 32) {
        short8v a8;
        if (bm + srow < M) {
            const float* ap = &A[(size_t)(bm + srow) * K + k0 + skq];
            float4 v0 = *reinterpret_cast<const float4*>(ap);
            float4 v1 = *reinterpret_cast<const float4*>(ap + 4);
            if constexpr (BN) {
                int kb = k0 + skq;
                v0.x = fmaxf((v0.x - muS[kb + 0]) * rsS[kb + 0], 0.f);
                v0.y = fmaxf((v0.y - muS[kb + 1]) * rsS[kb + 1], 0.f);
                v0.z = fmaxf((v0.z - muS[kb + 2]) * rsS[kb + 2], 0.f);
                v0.w = fmaxf((v0.w - muS[kb + 3]) * rsS[kb + 3], 0.f);
                v1.x = fmaxf((v1.x - muS[kb + 4]) * rsS[kb + 4], 0.f);
                v1.y = fmaxf((v1.y - muS[kb + 5]) * rsS[kb + 5], 0.f);
                v1.z = fmaxf((v1.z - muS[kb + 6]) * rsS[kb + 6], 0.f);
                v1.w = fmaxf((v1.w - muS[kb + 7]) * rsS[kb + 7], 0.f);
            }
            a8[0] = (short)f2bf(v0.x); a8[1] = (short)f2bf(v0.y);
            a8[2] = (short)f2bf(v0.z); a8[3] = (short)f2bf(v0.w);
            a8[4] = (short)f2bf(v1.x); a8[5] = (short)f2bf(v1.y);
            a8[6] = (short)f2bf(v1.z); a8[7] = (short)f2bf(v1.w);
        } else {
            a8 = (short8v){0,0,0,0,0,0,0,0};
        }
        short8v b8 = *reinterpret_cast<const short8v*>(&Wt[(size_t)(bn + srow) * K + k0 + skq]);
        __syncthreads();
        *reinterpret_cast<short8v*>(&As[srow * 40 + skq]) = a8;
        *reinterpret_cast<short8v*>(&Bs[srow * 40 + skq]) = b8;
        __syncthreads();
        short8v af = *reinterpret_cast<const short8v*>(&As[(w * 16 + l15) * 40 + g * 8]);
        #pragma unroll
        for (int nt = 0; nt < 4; nt++) {
            short8v bf = *reinterpret_cast<const short8v*>(&Bs[(nt * 16 + l15) * 40 + g * 8]);
            acc[nt] = __builtin_amdgcn_mfma_f32_16x16x32_bf16(af, bf, acc[nt], 0, 0, 0);
        }
    }

    if constexpr (ATT) {
        float wsv[4], wdv[4];
        #pragma unroll
        for (int nt = 0; nt < 4; nt++) {
            wsv[nt] = att_s[bn + nt * 16 + l15];
            wdv[nt] = att_d[bn + nt * 16 + l15];
        }
        #pragma unroll
        for (int reg = 0; reg < 4; reg++) {
            int row = bm + w * 16 + g * 4 + reg;
            float ps = 0.f, pd = 0.f;
            #pragma unroll
            for (int nt = 0; nt < 4; nt++) {
                float c = acc[nt][reg];
                ps += c * wsv[nt];
                pd += c * wdv[nt];
                if (row < M)
                    Cb[(size_t)row * Nc + bn + nt * 16 + l15] = f2bf(c);
            }
            #pragma unroll
            for (int off = 1; off < 16; off <<= 1) {
                ps += __shfl_xor(ps, off);
                pd += __shfl_xor(pd, off);
            }
            if (l15 == 0 && row < M) {
                int hh = bn >> 6;
                a_src[(size_t)row * H + hh] = ps;
                a_dst[(size_t)row * H + hh] = pd;
            }
        }
    } else {
        __shared__ float csum[64], csum2[64];
        if (tid < 64) { csum[tid] = 0.f; csum2[tid] = 0.f; }
        __syncthreads();
        #pragma unroll
        for (int reg = 0; reg < 4; reg++) {
            int row = bm + w * 16 + g * 4 + reg;
            if (row < M) {
                #pragma unroll
                for (int nt = 0; nt < 4; nt++) {
                    int cc = (bn + nt * 16 + l15) & 63;
                    float v = acc[nt][reg] + bias[bn + nt * 16 + l15];
                    Cf[(size_t)row * Nc + bn + nt * 16 + l15] = v;
                    atomicAdd(&csum[cc], v);
                    atomicAdd(&csum2[cc], v * v);
                }
            }
        }
        __syncthreads();
        if (tid < 64) {
            float* dst = ostats + (blockIdx.x & (NCOPY - 1)) * 128;
            atomicAdd(&dst[tid], csum[tid]);
            atomicAdd(&dst[64 + tid], csum2[tid]);
        }
    }
}

// ---------------- fused softmax aggregation + BN stats, H=4 ----------------
__global__ void k_agg4f(const unsigned short* __restrict__ hb,
                        const float* __restrict__ asrc, const float* __restrict__ adst,
                        const int* __restrict__ startp, const int* __restrict__ deg,
                        const int* __restrict__ col, const float* __restrict__ bias,
                        float* __restrict__ out, float* __restrict__ ostats, int n)
{
    __shared__ float stage[4][256];
    int wv = (blockIdx.x * blockDim.x + threadIdx.x) >> 6;
    int lane = threadIdx.x & 63;
    int w = threadIdx.x >> 6;
    float4 o = make_float4(0.f, 0.f, 0.f, 0.f);
    if (wv < n) {
        const int s0 = startp[wv], d = deg[wv];
        const int hs = lane >> 4;
        const float adh = adst[wv * 4 + hs];
        const float ws = __expf(lrelu(asrc[wv * 4 + hs] + adh));
        const size_t cb = (size_t)wv * 256 + (lane << 2);
        ushort4 v = *reinterpret_cast<const ushort4*>(&hb[cb]);
        float a0 = ws * bf2f(v.x), a1 = ws * bf2f(v.y);
        float a2 = ws * bf2f(v.z), a3 = ws * bf2f(v.w);
        float sm = ws;
        const int* crow = col + s0;
        int t = 0;
        for (; t + 4 <= d; t += 4) {
            int sA = crow[t], sB = crow[t + 1], sC = crow[t + 2], sD = crow[t + 3];
            float wA = __expf(lrelu(asrc[sA * 4 + hs] + adh));
            float wB = __expf(lrelu(asrc[sB * 4 + hs] + adh));
            float wC = __expf(lrelu(asrc[sC * 4 + hs] + adh));
            float wD = __expf(lrelu(asrc[sD * 4 + hs] + adh));
            ushort4 uA = *reinterpret_cast<const ushort4*>(&hb[(size_t)sA * 256 + (lane << 2)]);
            ushort4 uB = *reinterpret_cast<const ushort4*>(&hb[(size_t)sB * 256 + (lane << 2)]);
            ushort4 uC = *reinterpret_cast<const ushort4*>(&hb[(size_t)sC * 256 + (lane << 2)]);
            ushort4 uD = *reinterpret_cast<const ushort4*>(&hb[(size_t)sD * 256 + (lane << 2)]);
            sm += wA + wB + wC + wD;
            a0 += wA * bf2f(uA.x) + wB * bf2f(uB.x) + wC * bf2f(uC.x) + wD * bf2f(uD.x);
            a1 += wA * bf2f(uA.y) + wB * bf2f(uB.y) + wC * bf2f(uC.y) + wD * bf2f(uD.y);
            a2 += wA * bf2f(uA.z) + wB * bf2f(uB.z) + wC * bf2f(uC.z) + wD * bf2f(uD.z);
            a3 += wA * bf2f(uA.w) + wB * bf2f(uB.w) + wC * bf2f(uC.w) + wD * bf2f(uD.w);
        }
        for (; t < d; t++) {
            int s = crow[t];
            float ww = __expf(lrelu(asrc[s * 4 + hs] + adh));
            ushort4 u = *reinterpret_cast<const ushort4*>(&hb[(size_t)s * 256 + (lane << 2)]);
            sm += ww;
            a0 += ww * bf2f(u.x); a1 += ww * bf2f(u.y);
            a2 += ww * bf2f(u.z); a3 += ww * bf2f(u.w);
        }
        float rv = 1.f / (sm + 1e-16f);
        const float4 bv = *reinterpret_cast<const float4*>(&bias[lane << 2]);
        o.x = a0 * rv + bv.x; o.y = a1 * rv + bv.y;
        o.z = a2 * rv + bv.z; o.w = a3 * rv + bv.w;
        *reinterpret_cast<float4*>(&out[cb]) = o;
    }
    *reinterpret_cast<float4*>(&stage[w][lane << 2]) = o;
    __syncthreads();
    int tid = threadIdx.x;
    float s = 0.f, s2 = 0.f;
    #pragma unroll
    for (int k = 0; k < 4; k++) {
        float v = stage[k][tid];
        s += v; s2 += v * v;
    }
    float* dst = ostats + (blockIdx.x & (NCOPY - 1)) * 512;
    atomicAdd(&dst[tid], s);
    atomicAdd(&dst[256 + tid], s2);
}

// ---------------- fused softmax aggregation + BN stats, H=1 ----------------
__global__ void k_agg1f(const unsigned short* __restrict__ hb,
                        const float* __restrict__ asrc, const float* __restrict__ adst,
                        const int* __restrict__ startp, const int* __restrict__ deg,
                        const int* __restrict__ col, const float* __restrict__ bias,
                        float* __restrict__ out, float* __restrict__ ostats, int n)
{
    __shared__ float stage[4][64];
    int wv = (blockIdx.x * blockDim.x + threadIdx.x) >> 6;
    int lane = threadIdx.x & 63;
    int w = threadIdx.x >> 6;
    const int g = lane >> 4, l16 = lane & 15;
    float4 o = make_float4(0.f, 0.f, 0.f, 0.f);
    if (wv < n) {
        const int s0 = startp[wv], d = deg[wv];
        const float adv = adst[wv];
        const size_t cb = (size_t)wv * 64 + (l16 << 2);
        float a0 = 0.f, a1 = 0.f, a2 = 0.f, a3 = 0.f, sm = 0.f;
        if (g == 0) {
            float ww = __expf(lrelu(asrc[wv] + adv));
            ushort4 v = *reinterpret_cast<const ushort4*>(&hb[cb]);
            a0 = ww * bf2f(v.x); a1 = ww * bf2f(v.y);
            a2 = ww * bf2f(v.z); a3 = ww * bf2f(v.w);
            sm = ww;
        }
        #pragma unroll 2
        for (int t = g; t < d; t += 4) {
            int s = col[s0 + t];
            float ww = __expf(lrelu(asrc[s] + adv));
            ushort4 u = *reinterpret_cast<const ushort4*>(&hb[(size_t)s * 64 + (l16 << 2)]);
            sm += ww;
            a0 += ww * bf2f(u.x); a1 += ww * bf2f(u.y);
            a2 += ww * bf2f(u.z); a3 += ww * bf2f(u.w);
        }
        #pragma unroll
        for (int off = 16; off <= 32; off <<= 1) {
            a0 += __shfl_xor(a0, off); a1 += __shfl_xor(a1, off);
            a2 += __shfl_xor(a2, off); a3 += __shfl_xor(a3, off);
            sm += __shfl_xor(sm, off);
        }
        if (g == 0) {
            float rv = 1.f / (sm + 1e-16f);
            float4 bv = *reinterpret_cast<const float4*>(&bias[l16 << 2]);
            o.x = a0 * rv + bv.x; o.y = a1 * rv + bv.y;
            o.z = a2 * rv + bv.z; o.w = a3 * rv + bv.w;
            *reinterpret_cast<float4*>(&out[cb]) = o;
        }
    }
    if (g == 0)
        *reinterpret_cast<float4*>(&stage[w][l16 << 2]) = o;
    __syncthreads();
    int tid = threadIdx.x;
    if (tid < 64) {
        float s = 0.f, s2 = 0.f;
        #pragma unroll
        for (int k = 0; k < 4; k++) {
            float v = stage[k][tid];
            s += v; s2 += v * v;
        }
        float* dst = ostats + (blockIdx.x & (NCOPY - 1)) * 128;
        atomicAdd(&dst[tid], s);
        atomicAdd(&dst[64 + tid], s2);
    }
}

// ---------------- final head: relu(bn(h)) @ lw2 + lb2 ----------------
__global__ void k_head(const float* __restrict__ h, const float* __restrict__ bnst,
                       float invN,
                       const float* __restrict__ lw2, const float* __restrict__ lb2,
                       float* __restrict__ out, int n)
{
    __shared__ float muH[64], rsH[64];
    int tid = threadIdx.x;
    if (tid < 64) {
        float s = 0.f, s2 = 0.f;
        #pragma unroll
        for (int c = 0; c < NCOPY; c++) {
            s  += bnst[c * 128 + tid];
            s2 += bnst[c * 128 + 64 + tid];
        }
        float m = s * invN;
        float var = s2 * invN - m * m;
        muH[tid] = m;
        rsH[tid] = rsqrtf(var + EPS_BN);
    }
    __syncthreads();
    int wv = (blockIdx.x * blockDim.x + threadIdx.x) >> 6;
    int lane = threadIdx.x & 63;
    if (wv >= n) return;
    float v = fmaxf((h[(size_t)wv * 64 + lane] - muH[lane]) * rsH[lane], 0.f);
    float c0 = v * lw2[lane * 2 + 0];
    float c1 = v * lw2[lane * 2 + 1];
    #pragma unroll
    for (int off = 32; off; off >>= 1) {
        c0 += __shfl_xor(c0, off);
        c1 += __shfl_xor(c1, off);
    }
    if (lane == 0) {
        out[wv * 2 + 0] = c0 + lb2[0];
        out[wv * 2 + 1] = c1 + lb2[1];
    }
}

extern "C" void kernel_launch(void* const* d_in, const int* in_sizes, int n_in,
                              void* d_out, int out_size, void* d_ws, size_t ws_size,
                              hipStream_t stream)
{
    const float* x   = (const float*)d_in[0];
    const int*   ei  = (const int*)d_in[1];
    const float* W0  = (const float*)d_in[2];
    const float* as0 = (const float*)d_in[3];
    const float* ad0 = (const float*)d_in[4];
    const float* b0  = (const float*)d_in[5];
    const float* W1  = (const float*)d_in[6];
    const float* as1 = (const float*)d_in[7];
    const float* ad1 = (const float*)d_in[8];
    const float* b1  = (const float*)d_in[9];
    const float* W2  = (const float*)d_in[10];
    const float* as2 = (const float*)d_in[11];
    const float* ad2 = (const float*)d_in[12];
    const float* b2  = (const float*)d_in[13];
    const float* lw1 = (const float*)d_in[14];
    const float* lb1 = (const float*)d_in[15];
    const float* lw2 = (const float*)d_in[16];
    const float* lb2 = (const float*)d_in[17];
    float* out = (float*)d_out;

    const int n = in_sizes[0] / F_IN;   // 50000
    const int e = in_sizes[1] / 2;      // 800000

    char* ws = (char*)d_ws;
    size_t off = 0;
    auto alloc = [&](size_t bytes) -> void* {
        void* p = ws + off;
        off += (bytes + 255) & ~(size_t)255;
        return p;
    };
    float* B            = (float*)alloc((size_t)n * 256 * 4);           // agg outputs
    unsigned short* Hb  = (unsigned short*)alloc((size_t)n * 256 * 2);  // bf16 gather buf
    float* g3           = (float*)Hb;                                   // alias (Hb dead by MLP)
    float* a_src = (float*)alloc((size_t)n * 4 * 4);
    float* a_dst = (float*)alloc((size_t)n * 4 * 4);
    unsigned short* Wt0 = (unsigned short*)alloc(256 * 128 * 2);
    unsigned short* Wt1 = (unsigned short*)alloc(64 * 256 * 2);
    unsigned short* Wt2 = (unsigned short*)alloc(64 * 64 * 2);
    unsigned short* Wtm = (unsigned short*)alloc(64 * 64 * 2);
    int* col    = (int*)alloc((size_t)e * 4);
    int* startp = (int*)alloc((size_t)n * 4);
    // ---- contiguous zero-init region: stats (8-copy), deg, fill, cursor ----
    char* zbase = ws + off;
    float* st0 = (float*)alloc(NCOPY * 512 * 4);   // 8 x (sum[256], sumsq[256])
    float* st1 = (float*)alloc(NCOPY * 128 * 4);
    float* st2 = (float*)alloc(NCOPY * 128 * 4);
    float* st3 = (float*)alloc(NCOPY * 128 * 4);
    int* deg    = (int*)alloc((size_t)n * 4);
    int* fill   = (int*)alloc((size_t)n * 4);
    int* cursor = (int*)alloc(256);
    size_t zsize = (size_t)((ws + off) - zbase);

    const float invN = 1.f / (float)n;

    hipMemsetAsync(zbase, 0, zsize, stream);

    const int tpb = 256;
    k_wprep_all<<<(57344 + tpb - 1) / tpb, tpb, 0, stream>>>(W0, W1, W2, lw1, Wt0, Wt1, Wt2, Wtm);

    k_deg<<<(e + tpb - 1) / tpb, tpb, 0, stream>>>(ei, e, deg);
    k_offsets<<<(n + tpb - 1) / tpb, tpb, 0, stream>>>(deg, startp, cursor, n);
    k_fill<<<(e + tpb - 1) / tpb, tpb, 0, stream>>>(ei, e, startp, fill, col);

    const int wgrid = (n + 3) / 4;
    const int rowTiles = (n + 63) / 64;

    // Layer 0: GAT 128 -> 4x64
    k_gemm<false, true><<<dim3(rowTiles, 4), 256, 0, stream>>>(
        x, Wt0, nullptr, nullptr, invN, as0, ad0, a_src, a_dst, 4,
        nullptr, Hb, nullptr, n, 128, 256);
    k_agg4f<<<wgrid, 256, 0, stream>>>(Hb, a_src, a_dst, startp, deg, col, b0, B, st0, n);

    // Layer 1: GAT 256 -> 64 (BN+ReLU fused into A-load from st0)
    k_gemm<true, true><<<dim3(rowTiles, 1), 256, 0, stream>>>(
        B, Wt1, nullptr, st0, invN, as1, ad1, a_src, a_dst, 1,
        nullptr, Hb, nullptr, n, 256, 64);
    k_agg1f<<<wgrid, 256, 0, stream>>>(Hb, a_src, a_dst, startp, deg, col, b1, B, st1, n);

    // Layer 2: GAT 64 -> 64
    k_gemm<true, true><<<dim3(rowTiles, 1), 256, 0, stream>>>(
        B, Wt2, nullptr, st1, invN, as2, ad2, a_src, a_dst, 1,
        nullptr, Hb, nullptr, n, 64, 64);
    k_agg1f<<<wgrid, 256, 0, stream>>>(Hb, a_src, a_dst, startp, deg, col, b2, B, st2, n);

    // MLP: relu(bn(o2)) @ lw1 + lb1, stats of output into st3
    k_gemm<true, false><<<dim3(rowTiles, 1), 256, 0, stream>>>(
        B, Wtm, lb1, st2, invN, nullptr, nullptr, nullptr, nullptr, 1,
        g3, nullptr, st3, n, 64, 64);

    // head: relu(bn(g3)) @ lw2 + lb2
    k_head<<<wgrid, 256, 0, stream>>>(g3, st3, invN, lw2, lb2, out, n);
}